// Round 8
// baseline (273.917 us; speedup 1.0000x reference)
//
#include <hip/hip_runtime.h>
#include <cstdint>
#include <cstddef>

#define B_ 8
#define N_ 4096
#define C_ 512
#define KV_ 960
#define DQ 128
#define DK 240
#define NSPLIT 8   // k1 split-K: grid 32*8 = 256 blocks

typedef __attribute__((ext_vector_type(8))) short bf16x8;
typedef __attribute__((ext_vector_type(4))) float f32x4;
#define AS1 __attribute__((address_space(1)))
#define AS3 __attribute__((address_space(3)))

__device__ __forceinline__ ushort f2bf(float f) {
  uint32_t u = __float_as_uint(f);
  u += 0x7FFFu + ((u >> 16) & 1u);  // RNE
  return (ushort)(u >> 16);
}

// ---------------------------------------------------------------------------
// Transpose + cvt: in f32 [b][4096][CH]  ->  out bf16 [b][CH][4096].
// 64n x 64c tile per block, LDS-staged; coalesced reads and writes.
// grid (64 nt, CH/64 ct, 8 b), block 256.
// ---------------------------------------------------------------------------
__global__ __launch_bounds__(256) void k_tr(const float* __restrict__ in,
                                            ushort* __restrict__ out, int CH) {
  __shared__ ushort st[64][80];  // [c][n], stride 160B (16B-aligned rows)
  const int n0 = blockIdx.x * 64;
  const int c0 = blockIdx.y * 64;
  const int b = blockIdx.z;
  const int t = threadIdx.x;
  const int nr = t >> 2, cg = t & 3;
  const float* src = in + ((size_t)b * N_ + n0 + nr) * CH + c0 + cg * 16;
  float4 v[4];
#pragma unroll
  for (int q = 0; q < 4; ++q) v[q] = *(const float4*)(src + q * 4);
#pragma unroll
  for (int q = 0; q < 4; ++q) {
    st[cg * 16 + q * 4 + 0][nr] = f2bf(v[q].x);
    st[cg * 16 + q * 4 + 1][nr] = f2bf(v[q].y);
    st[cg * 16 + q * 4 + 2][nr] = f2bf(v[q].z);
    st[cg * 16 + q * 4 + 3][nr] = f2bf(v[q].w);
  }
  __syncthreads();
  const int cr = t >> 2, ng = t & 3;
  ushort* dst = out + ((size_t)b * CH + c0 + cr) * N_ + n0 + ng * 16;
  *(bf16x8*)(dst) = *(const bf16x8*)(&st[cr][ng * 16]);
  *(bf16x8*)(dst + 8) = *(const bf16x8*)(&st[cr][ng * 16 + 8]);
}

// ---------------------------------------------------------------------------
// f32 -> bf16 (RNE), 4 elems/thread (row-major copy for k3)
// ---------------------------------------------------------------------------
__global__ __launch_bounds__(256) void k_cvt(const float4* __restrict__ in,
                                             ushort4* __restrict__ out, int n4) {
  int i = blockIdx.x * 256 + threadIdx.x;
  if (i >= n4) return;
  float4 v = in[i];
  ushort4 o;
  o.x = f2bf(v.x); o.y = f2bf(v.y); o.z = f2bf(v.z); o.w = f2bf(v.w);
  out[i] = o;
}

// ---------------------------------------------------------------------------
// K1 v4 (MFMA, NT, fully coalesced): partial
//   S[b,h,i,j] = sum_{n in split} emb1T[b][h*128+i][n] * embaT[b][h*240+j][n]
// Per block (bh, split): 128i x 256j (240 valid), K = 512 n, BK = 32.
// Both operands staged via global_load_lds (coalesced 64B rows, source
// chunk-permuted c^= (row>>1)&3); ds_read_b128 with matching XOR (2-way max).
// Double-buffered 24KB bufs (48KB total -> 3 blocks/CU), counted vmcnt(3).
// grid (32 bh, NSPLIT), block 512 (8 waves 2x4; wave tile 64x64).
// ---------------------------------------------------------------------------
__global__ __launch_bounds__(512) void k1_nt(const ushort* __restrict__ emb1T,
                                             const ushort* __restrict__ embaT,
                                             float* __restrict__ P) {
  __shared__ ushort LDS_[2 * 12288];  // per buf: A 4096 us (8KB) + B 8192 us (16KB)
  const int bh = blockIdx.x;
  const int split = blockIdx.y;
  const int b = bh >> 2, h = bh & 3;
  const int t = threadIdx.x;
  const int w = t >> 6, l = t & 63;
  const int wr = w >> 2, wc = w & 3;  // wave tile rows wr*64, cols wc*64
  const int n0 = split * (N_ / NSPLIT);

  // ---- staging sources (coalesced rows; 16B chunks permuted within row) ----
  const int d = l >> 2, cp = l & 3;
  const int rA = w * 16 + d;                       // A tile row (i), 0..127
  const int cA = cp ^ ((rA >> 1) & 3);
  const ushort* srcA = emb1T + ((size_t)(b * 512 + h * 128 + rA) << 12) + n0 + cA * 8;
  const int jB0 = (w * 2 + 0) * 16 + d;            // B tile rows (j), 0..255
  const int jB1 = (w * 2 + 1) * 16 + d;
  const int cB0 = cp ^ ((jB0 >> 1) & 3);
  const int cB1 = cp ^ ((jB1 >> 1) & 3);
  const ushort* srcB0 =
      embaT + ((size_t)(b * 960 + h * 240 + (jB0 < 240 ? jB0 : 239)) << 12) + n0 + cB0 * 8;
  const ushort* srcB1 =
      embaT + ((size_t)(b * 960 + h * 240 + (jB1 < 240 ? jB1 : 239)) << 12) + n0 + cB1 * 8;
  // LDS dests (linear, bytes)
  const uint dA = (uint)(w * 1024 + l * 16);
  const uint dB0 = (uint)(8192 + (w * 2 + 0) * 1024 + l * 16);
  const uint dB1 = (uint)(8192 + (w * 2 + 1) * 1024 + l * 16);
  char* LDSb = (char*)LDS_;

#define STAGE(tile, bf)                                                         \
  do {                                                                          \
    __builtin_amdgcn_global_load_lds(                                           \
        (AS1 const uint32_t*)(uintptr_t)(srcA + (size_t)(tile) * 32),           \
        (AS3 uint32_t*)(uintptr_t)(LDSb + (bf) * 24576 + dA), 16, 0, 0);        \
    __builtin_amdgcn_global_load_lds(                                           \
        (AS1 const uint32_t*)(uintptr_t)(srcB0 + (size_t)(tile) * 32),          \
        (AS3 uint32_t*)(uintptr_t)(LDSb + (bf) * 24576 + dB0), 16, 0, 0);       \
    __builtin_amdgcn_global_load_lds(                                           \
        (AS1 const uint32_t*)(uintptr_t)(srcB1 + (size_t)(tile) * 32),          \
        (AS3 uint32_t*)(uintptr_t)(LDSb + (bf) * 24576 + dB1), 16, 0, 0);       \
  } while (0)

  f32x4 acc[4][4];
#pragma unroll
  for (int fm = 0; fm < 4; ++fm)
#pragma unroll
    for (int fn = 0; fn < 4; ++fn) acc[fm][fn] = (f32x4){0.f, 0.f, 0.f, 0.f};

  // fragment read offsets (ushort units): row*32 + (kb^((l>>1)&3))*8
  const int xk = (l >> 4) ^ ((l >> 1) & 3);
  int offA[4], offB[4];
#pragma unroll
  for (int f = 0; f < 4; ++f) {
    offA[f] = (wr * 64 + f * 16 + (l & 15)) * 32 + xk * 8;
    offB[f] = 4096 + (wc * 64 + f * 16 + (l & 15)) * 32 + xk * 8;
  }

  STAGE(0, 0);
  for (int ks = 0; ks < 16; ++ks) {
    const int buf = ks & 1;
    if (ks < 15) {
      STAGE(ks + 1, buf ^ 1);
      asm volatile("s_waitcnt vmcnt(3)" ::: "memory");
    } else {
      asm volatile("s_waitcnt vmcnt(0)" ::: "memory");
    }
    __builtin_amdgcn_sched_barrier(0);
    __builtin_amdgcn_s_barrier();
    const int bb = buf * 12288;
    bf16x8 af[4], bv[4];
#pragma unroll
    for (int f = 0; f < 4; ++f) af[f] = *(const bf16x8*)(LDS_ + bb + offA[f]);
#pragma unroll
    for (int f = 0; f < 4; ++f) bv[f] = *(const bf16x8*)(LDS_ + bb + offB[f]);
#pragma unroll
    for (int fm = 0; fm < 4; ++fm)
#pragma unroll
      for (int fn = 0; fn < 4; ++fn)
        acc[fm][fn] = __builtin_amdgcn_mfma_f32_16x16x32_bf16(af[fm], bv[fn],
                                                              acc[fm][fn], 0, 0, 0);
    __builtin_amdgcn_s_barrier();
  }
#undef STAGE

  // fragment-native coalesced store: P[split][bh][v=fm*4+fn][t] (f32x4)
  f32x4* Pv4 = (f32x4*)P + (size_t)(split * 32 + bh) * 8192;
#pragma unroll
  for (int fm = 0; fm < 4; ++fm)
#pragma unroll
    for (int fn = 0; fn < 4; ++fn) Pv4[(fm * 4 + fn) * 512 + t] = acc[fm][fn];
}

// ---------------------------------------------------------------------------
// Reduce NSPLIT fragment-native partials, un-swizzle into S[bh][128][240].
// grid (32 bh, 32), block 256.  (unchanged from R7)
// ---------------------------------------------------------------------------
__global__ __launch_bounds__(256) void k_reduce_frag(const f32x4* __restrict__ P,
                                                     float* __restrict__ S) {
  const int bh = blockIdx.x;
  const int g = blockIdx.y * 256 + threadIdx.x;  // 0..8191
  f32x4 a = P[(size_t)bh * 8192 + g];
#pragma unroll
  for (int s = 1; s < NSPLIT; ++s) {
    f32x4 v = P[(size_t)s * 262144 + (size_t)bh * 8192 + g];
    a.x += v.x; a.y += v.y; a.z += v.z; a.w += v.w;
  }
  const int v = g >> 9, tt = g & 511;
  const int fm = v >> 2, fn = v & 3;
  const int wv = tt >> 6, l = tt & 63;
  const int wr = wv >> 2, wc = wv & 3;
  const int i0 = wr * 64 + fm * 16 + (l >> 4) * 4;
  const int j = wc * 64 + fn * 16 + (l & 15);
  if (j < DK) {
    float* sp = S + (size_t)bh * (DQ * DK) + (size_t)i0 * DK + j;
    sp[0] = a.x; sp[DK] = a.y; sp[2 * DK] = a.z; sp[3 * DK] = a.w;
  }
}

// ===========================================================================
// Flat-batched f32 chain GEMMs (unchanged from R6/R7).
// ===========================================================================
__global__ __launch_bounds__(256) void k_g1(const float* __restrict__ Wq,
                                            const float* __restrict__ S,
                                            float* __restrict__ U) {
  const int h = blockIdx.x, c0 = blockIdx.y * 64;
  const int b = blockIdx.z / 5, n0 = (blockIdx.z % 5) * 48;
  const float* A = Wq + (size_t)h * 16384;
  const float* Bp = S + (size_t)(b * 4 + h) * 30720 + n0;
  float* Cp = U + (size_t)(b * 4 + h) * 30720 + n0;
  __shared__ float Ast[16][65];
  __shared__ float Bst[16][49];
  const int t = threadIdx.x;
  const int mi = (t >> 4) * 4, nj = (t & 15) * 3;
  float acc[4][3] = {};
  for (int k0 = 0; k0 < 128; k0 += 16) {
    __syncthreads();
#pragma unroll
    for (int q = 0; q < 4; ++q) {
      int idx = t + q * 256, m = idx >> 4, k = idx & 15;
      Ast[k][m] = A[(size_t)(c0 + m) * 128 + k0 + k];
    }
#pragma unroll
    for (int q = 0; q < 3; ++q) {
      int idx = t + q * 256, k = idx / 48, n = idx % 48;
      Bst[k][n] = Bp[(size_t)(k0 + k) * 240 + n];
    }
    __syncthreads();
#pragma unroll
    for (int kk = 0; kk < 16; ++kk) {
      float a4[4], b3[3];
#pragma unroll
      for (int x = 0; x < 4; ++x) a4[x] = Ast[kk][mi + x];
#pragma unroll
      for (int y = 0; y < 3; ++y) b3[y] = Bst[kk][nj + y];
#pragma unroll
      for (int x = 0; x < 4; ++x)
#pragma unroll
        for (int y = 0; y < 3; ++y) acc[x][y] = fmaf(a4[x], b3[y], acc[x][y]);
    }
  }
#pragma unroll
  for (int x = 0; x < 4; ++x)
#pragma unroll
    for (int y = 0; y < 3; ++y)
      Cp[(size_t)(c0 + mi + x) * 240 + nj + y] = acc[x][y];
}

__global__ __launch_bounds__(256) void k_g2(const float* __restrict__ U,
                                            const float* __restrict__ Wk,
                                            float* __restrict__ SC) {
  const int m0 = blockIdx.x * 64, n0 = blockIdx.y * 48;
  __shared__ float Ast[16][65];
  __shared__ float Bst2[48][17];
  const int t = threadIdx.x;
  const int mi = (t >> 4) * 4, nj = (t & 15) * 3;
  float acc[4][3] = {};
  for (int k0 = 0; k0 < 240; k0 += 16) {
    __syncthreads();
#pragma unroll
    for (int q = 0; q < 4; ++q) {
      int idx = t + q * 256, m = idx >> 4, k = idx & 15;
      Ast[k][m] = U[(size_t)(m0 + m) * 240 + k0 + k];
    }
#pragma unroll
    for (int q = 0; q < 3; ++q) {
      int idx = t + q * 256, n = idx >> 4, kd = idx & 15;
      Bst2[n][kd] = Wk[(size_t)(n0 + n) * 240 + k0 + kd];
    }
    __syncthreads();
#pragma unroll
    for (int kk = 0; kk < 16; ++kk) {
      float a4[4], b3[3];
#pragma unroll
      for (int x = 0; x < 4; ++x) a4[x] = Ast[kk][mi + x];
#pragma unroll
      for (int y = 0; y < 3; ++y) b3[y] = Bst2[nj + y][kk];
#pragma unroll
      for (int x = 0; x < 4; ++x)
#pragma unroll
        for (int y = 0; y < 3; ++y) acc[x][y] = fmaf(a4[x], b3[y], acc[x][y]);
    }
  }
  const float scale = 0.0322748612183951f;
#pragma unroll
  for (int x = 0; x < 4; ++x)
#pragma unroll
    for (int y = 0; y < 3; ++y)
      SC[(size_t)(m0 + mi + x) * 240 + n0 + nj + y] = acc[x][y] * scale;
}

__global__ __launch_bounds__(256) void k_g3(const float* __restrict__ PR,
                                            const float* __restrict__ Wv,
                                            float* __restrict__ T) {
  const int m0 = blockIdx.x * 64, n0 = blockIdx.y * 48;
  __shared__ float Ast[16][65];
  __shared__ float Bst[16][49];
  const int t = threadIdx.x;
  const int mi = (t >> 4) * 4, nj = (t & 15) * 3;
  float acc[4][3] = {};
  for (int k0 = 0; k0 < 240; k0 += 16) {
    __syncthreads();
#pragma unroll
    for (int q = 0; q < 4; ++q) {
      int idx = t + q * 256, m = idx >> 4, k = idx & 15;
      Ast[k][m] = PR[(size_t)(m0 + m) * 240 + k0 + k];
    }
#pragma unroll
    for (int q = 0; q < 3; ++q) {
      int idx = t + q * 256, k = idx / 48, n = idx % 48;
      Bst[k][n] = Wv[(size_t)(k0 + k) * 240 + n0 + n];
    }
    __syncthreads();
#pragma unroll
    for (int kk = 0; kk < 16; ++kk) {
      float a4[4], b3[3];
#pragma unroll
      for (int x = 0; x < 4; ++x) a4[x] = Ast[kk][mi + x];
#pragma unroll
      for (int y = 0; y < 3; ++y) b3[y] = Bst[kk][nj + y];
#pragma unroll
      for (int x = 0; x < 4; ++x)
#pragma unroll
        for (int y = 0; y < 3; ++y) acc[x][y] = fmaf(a4[x], b3[y], acc[x][y]);
    }
  }
#pragma unroll
  for (int x = 0; x < 4; ++x)
#pragma unroll
    for (int y = 0; y < 3; ++y)
      T[(size_t)(m0 + mi + x) * 240 + n0 + nj + y] = acc[x][y];
}

__global__ __launch_bounds__(256) void k_g4(const float* __restrict__ Wo,
                                            const float* __restrict__ T,
                                            ushort* __restrict__ W3bf) {
  const int h = blockIdx.x, e0 = blockIdx.y * 64;
  const int b = blockIdx.z / 5, n0 = (blockIdx.z % 5) * 48;
  const float* Bp = T + (size_t)(b * 4 + h) * 30720 + n0;
  ushort* Cp = W3bf + (size_t)b * 491520 + h * 240 + n0;
  __shared__ float Ast[16][65];
  __shared__ float Bst[16][49];
  const int t = threadIdx.x;
  const int mi = (t >> 4) * 4, nj = (t & 15) * 3;
  float acc[4][3] = {};
  for (int k0 = 0; k0 < 128; k0 += 16) {
    __syncthreads();
#pragma unroll
    for (int q = 0; q < 4; ++q) {
      int idx = t + q * 256, m = idx >> 4, k = idx & 15;
      Ast[k][m] = Wo[(size_t)(e0 + m) * 512 + 4 * (k0 + k) + h];
    }
#pragma unroll
    for (int q = 0; q < 3; ++q) {
      int idx = t + q * 256, k = idx / 48, n = idx % 48;
      Bst[k][n] = Bp[(size_t)(k0 + k) * 240 + n];
    }
    __syncthreads();
#pragma unroll
    for (int kk = 0; kk < 16; ++kk) {
      float a4[4], b3[3];
#pragma unroll
      for (int x = 0; x < 4; ++x) a4[x] = Ast[kk][mi + x];
#pragma unroll
      for (int y = 0; y < 3; ++y) b3[y] = Bst[kk][nj + y];
#pragma unroll
      for (int x = 0; x < 4; ++x)
#pragma unroll
        for (int y = 0; y < 3; ++y) acc[x][y] = fmaf(a4[x], b3[y], acc[x][y]);
    }
  }
#pragma unroll
  for (int x = 0; x < 4; ++x)
#pragma unroll
    for (int y = 0; y < 3; ++y)
      Cp[(size_t)(e0 + mi + x) * 960 + nj + y] = f2bf(acc[x][y]);
}

// ---------------------------------------------------------------------------
// Stats + softmax (unchanged).
// ---------------------------------------------------------------------------
__global__ __launch_bounds__(1024) void k_stats(const float* __restrict__ SC,
                                                float* __restrict__ stats) {
  const int bh = blockIdx.x;
  const float* s = SC + (size_t)bh * 30720;
  const int t = threadIdx.x;
  float sum = 0.f, sq = 0.f;
  for (int i = t; i < 30720; i += 1024) {
    float v = s[i];
    sum += v;
    sq = fmaf(v, v, sq);
  }
#pragma unroll
  for (int o = 32; o > 0; o >>= 1) {
    sum += __shfl_down(sum, o);
    sq += __shfl_down(sq, o);
  }
  __shared__ float s1[16], s2[16];
  if ((t & 63) == 0) { s1[t >> 6] = sum; s2[t >> 6] = sq; }
  __syncthreads();
  if (t == 0) {
    float ts = 0.f, tq = 0.f;
#pragma unroll
    for (int i = 0; i < 16; ++i) { ts += s1[i]; tq += s2[i]; }
    const float mu = ts * (1.f / 30720.f);
    const float var = tq * (1.f / 30720.f) - mu * mu;
    stats[bh * 2] = mu;
    stats[bh * 2 + 1] = rsqrtf(var + 1e-5f);
  }
}

__global__ __launch_bounds__(512) void k_softmax(const float* __restrict__ SC,
                                                 const float* __restrict__ stats,
                                                 float* __restrict__ PR) {
  const int bh = blockIdx.x;
  const float mu = stats[bh * 2], rstd = stats[bh * 2 + 1];
  const int wv = threadIdx.x >> 6, l = threadIdx.x & 63;
  const int row0 = blockIdx.y * 32 + wv * 4;
  const float* s = SC + (size_t)bh * 30720;
  float* p = PR + (size_t)bh * 30720;
#pragma unroll
  for (int r = 0; r < 4; ++r) {
    const float* srow = s + (size_t)(row0 + r) * 240;
    float* prow = p + (size_t)(row0 + r) * 240;
    float x0 = (srow[l] - mu) * rstd;
    float x1 = (srow[64 + l] - mu) * rstd;
    float x2 = (srow[128 + l] - mu) * rstd;
    float x3 = (l < 48) ? (srow[192 + l] - mu) * rstd : -1e30f;
    float m = fmaxf(fmaxf(x0, x1), fmaxf(x2, x3));
#pragma unroll
    for (int o = 32; o > 0; o >>= 1) m = fmaxf(m, __shfl_xor(m, o));
    float e0 = __expf(x0 - m), e1 = __expf(x1 - m), e2 = __expf(x2 - m);
    float e3 = (l < 48) ? __expf(x3 - m) : 0.f;
    float ss = e0 + e1 + e2 + e3;
#pragma unroll
    for (int o = 32; o > 0; o >>= 1) ss += __shfl_xor(ss, o);
    const float inv = 1.f / ss;
    prow[l] = e0 * inv;
    prow[64 + l] = e1 * inv;
    prow[128 + l] = e2 * inv;
    if (l < 48) prow[192 + l] = e3 * inv;
  }
}

// ---------------------------------------------------------------------------
// K3 (MFMA): unchanged (128x128 tile, XCD-swizzled flat grid).
// ---------------------------------------------------------------------------
__global__ __launch_bounds__(256) void k3_mfma(const ushort* __restrict__ A,
                                               const ushort* __restrict__ Bw,
                                               float* __restrict__ C) {
  __shared__ ushort As[128 * 32];
  __shared__ ushort Bs[128 * 32];
  const int bid = blockIdx.x;
  const int swz = (bid & 7) * 128 + (bid >> 3);
  const int b = swz >> 7;
  const int rem = swz & 127;
  const int mt = rem >> 2, nt = rem & 3;
  const int t = threadIdx.x;
  const int w = t >> 6, l = t & 63;
  const int wr = w >> 1, wc = w & 1;

  const ushort* Ab = A + (size_t)b * N_ * KV_ + (size_t)mt * 128 * KV_;
  const ushort* Bb = Bw + (size_t)b * C_ * KV_ + (size_t)nt * 128 * KV_;

  const int r_l = l >> 2;
  const int c_l = (l & 3) * 8;

  f32x4 acc[4][4];
#pragma unroll
  for (int fm = 0; fm < 4; ++fm)
#pragma unroll
    for (int fn = 0; fn < 4; ++fn) acc[fm][fn] = (f32x4){0.f, 0.f, 0.f, 0.f};

  const int lrow = l & 15;
  const int lk = (l >> 4) * 8;

  for (int k0 = 0; k0 < KV_; k0 += 32) {
#pragma unroll
    for (int inst = 0; inst < 2; ++inst) {
      const int gi = w * 2 + inst;
      const ushort* ga = Ab + (size_t)(gi * 16 + r_l) * KV_ + k0 + c_l;
      __builtin_amdgcn_global_load_lds((AS1 const uint32_t*)(uintptr_t)ga,
                                       (AS3 uint32_t*)(uintptr_t)(As + gi * 512),
                                       16, 0, 0);
      const ushort* gb = Bb + (size_t)(gi * 16 + r_l) * KV_ + k0 + c_l;
      __builtin_amdgcn_global_load_lds((AS1 const uint32_t*)(uintptr_t)gb,
                                       (AS3 uint32_t*)(uintptr_t)(Bs + gi * 512),
                                       16, 0, 0);
    }
    __syncthreads();
    bf16x8 af[4], bfr[4];
#pragma unroll
    for (int fm = 0; fm < 4; ++fm)
      af[fm] = *(const bf16x8*)(As + (wr * 64 + fm * 16 + lrow) * 32 + lk);
#pragma unroll
    for (int fn = 0; fn < 4; ++fn)
      bfr[fn] = *(const bf16x8*)(Bs + (wc * 64 + fn * 16 + lrow) * 32 + lk);
#pragma unroll
    for (int fm = 0; fm < 4; ++fm)
#pragma unroll
      for (int fn = 0; fn < 4; ++fn)
        acc[fm][fn] = __builtin_amdgcn_mfma_f32_16x16x32_bf16(af[fm], bfr[fn],
                                                              acc[fm][fn], 0, 0, 0);
    __syncthreads();
  }

  float* Cb = C + (size_t)b * N_ * C_ + ((size_t)mt * 128) * C_ + nt * 128;
  const int col = wc * 64 + (l & 15);
  const int rbase = wr * 64 + (l >> 4) * 4;
#pragma unroll
  for (int fm = 0; fm < 4; ++fm)
#pragma unroll
    for (int fn = 0; fn < 4; ++fn)
#pragma unroll
      for (int r = 0; r < 4; ++r)
        Cb[(size_t)(rbase + fm * 16 + r) * C_ + col + fn * 16] = acc[fm][fn][r];
}

// ---------------------------------------------------------------------------
// Memory plan (ws 78,643,200 B + d_out 67,108,864 B as scratch):
//   d_out [0, 33554432)          P frag-partials   -- dead before k3
//   d_out [33554432, 67108864)   emb1T (bf16 [b][512][4096]) -- dead before k3
//   ws [0, 62914560)             embaT (bf16 [b][960][4096]) during k1,
//                                then OVERWRITTEN by embaBF row-major (k_cvt)
//   ws [62914560, 66846720)      S (f32) -> then T (f32, after g1)
//   ws [66846720, 70778880)      U (f32); stats overlays after g2; W3bf later
//   ws [70778880, 74711040)      SC (f32)  } W3bf (bf16) overlays U+SC in g4
//   ws [74711040, 78643200)      PR (f32)
// ---------------------------------------------------------------------------
extern "C" void kernel_launch(void* const* d_in, const int* in_sizes, int n_in,
                              void* d_out, int out_size, void* d_ws, size_t ws_size,
                              hipStream_t stream) {
  const float* emb1 = (const float*)d_in[0];
  const float* emba = (const float*)d_in[1];
  const float* Wq   = (const float*)d_in[2];
  const float* Wk   = (const float*)d_in[3];
  const float* Wv   = (const float*)d_in[4];
  const float* Wo   = (const float*)d_in[5];
  float* out = (float*)d_out;
  char* ws = (char*)d_ws;

  ushort* embaT  = (ushort*)(ws);
  ushort* embaBF = (ushort*)(ws);
  float*  S      = (float*)(ws + 62914560);
  float*  T      = (float*)(ws + 62914560);
  float*  U      = (float*)(ws + 66846720);
  ushort* W3bf   = (ushort*)(ws + 66846720);
  float*  SCb    = (float*)(ws + 70778880);
  float*  PRb    = (float*)(ws + 74711040);
  float*  P      = out;
  ushort* emb1T  = (ushort*)((char*)d_out + 33554432);
  float*  stats  = (float*)(ws + 66846720);  // U region, dead after g2

  // 1) transpose+cvt both inputs to n-contiguous bf16
  k_tr<<<dim3(64, 8, 8), 256, 0, stream>>>(emb1, emb1T, 512);
  k_tr<<<dim3(64, 15, 8), 256, 0, stream>>>(emba, embaT, 960);

  // 2) S partials (coalesced NT MFMA) + reduce/unswizzle
  k1_nt<<<dim3(32, NSPLIT), 512, 0, stream>>>(emb1T, embaT, P);
  k_reduce_frag<<<dim3(32, 32), 256, 0, stream>>>((const f32x4*)P, S);

  // 3) emba -> bf16 row-major for k3 (overwrites embaT, now dead)
  k_cvt<<<30720, 256, 0, stream>>>((const float4*)emba, (ushort4*)embaBF, 7864320);

  // 4) chain (flat-batched f32 GEMMs + stats + softmax)
  k_g1<<<dim3(4, 2, 40), 256, 0, stream>>>(Wq, S, U);
  k_g2<<<dim3(64, 5), 256, 0, stream>>>(U, Wk, SCb);
  k_stats<<<32, 1024, 0, stream>>>(SCb, stats);
  k_softmax<<<dim3(32, 4), 512, 0, stream>>>(SCb, stats, PRb);
  k_g3<<<dim3(64, 5), 256, 0, stream>>>(PRb, Wv, T);
  k_g4<<<dim3(4, 8, 40), 256, 0, stream>>>(Wo, T, W3bf);

  // 5) O1[b] = embaBF[b] @ W3bf[b]^T  (MFMA, XCD-swizzled)
  k3_mfma<<<1024, 256, 0, stream>>>(embaBF, W3bf, out);
}

// Round 9
// 257.199 us; speedup vs baseline: 1.0650x; 1.0650x over previous
//
#include <hip/hip_runtime.h>
#include <cstdint>
#include <cstddef>

#define B_ 8
#define N_ 4096
#define C_ 512
#define KV_ 960
#define DQ 128
#define DK 240
#define NSPLIT 8   // split-K over n for k1; grid 32*8*2 = 512 blocks = 2/CU

typedef __attribute__((ext_vector_type(8))) short bf16x8;
typedef __attribute__((ext_vector_type(4))) float f32x4;
#define AS1 __attribute__((address_space(1)))
#define AS3 __attribute__((address_space(3)))

__device__ __forceinline__ ushort f2bf(float f) {
  uint32_t u = __float_as_uint(f);
  u += 0x7FFFu + ((u >> 16) & 1u);  // RNE
  return (ushort)(u >> 16);
}

__device__ __forceinline__ uint32_t cvtpk(float lo, float hi) {
  uint32_t r;
  asm("v_cvt_pk_bf16_f32 %0, %1, %2" : "=v"(r) : "v"(lo), "v"(hi));
  return r;
}

union bfpack {
  uint32_t u[4];
  ushort s[8];
  bf16x8 v;
};

// ---------------------------------------------------------------------------
// K1 (MFMA, 2 blocks/CU, gather-staged): partial
//   S[b,h,i,j] = sum_{n in split} emb1[b,n,h*128+i] * embaBF[b,n,h*240+j]
// (R6-proven version, unchanged)
// ---------------------------------------------------------------------------
__global__ __launch_bounds__(512) void k1_mfma(const float* __restrict__ emb1,
                                               const ushort* __restrict__ embaBF,
                                               float* __restrict__ P) {
  __shared__ ushort As[128 * 64];
  __shared__ ushort Bs[128 * 64];
  const int bh = blockIdx.x;
  const int split = blockIdx.y;
  const int jh = blockIdx.z;
  const int b = bh >> 2, h = bh & 3;
  const int t = threadIdx.x;
  const int w = t >> 6, l = t & 63;
  const int wm = w >> 1, wn = w & 1;

  const float* Abase = emb1 + (size_t)b * N_ * C_ + h * DQ;
  const ushort* Bbase = embaBF + (size_t)b * N_ * KV_;

  const int cA = t & 127;
  const int jB = t & 127;
  const int nb0 = t >> 7;
  int jl = jh * 128 + jB;
  if (jl > DK - 1) jl = DK - 1;
  const int jg = h * DK + jl;

  f32x4 acc[2][4];
#pragma unroll
  for (int fm = 0; fm < 2; ++fm)
#pragma unroll
    for (int fn = 0; fn < 4; ++fn) acc[fm][fn] = (f32x4){0.f, 0.f, 0.f, 0.f};

  const int n0 = split * (N_ / NSPLIT);
  const int lrow = l & 15;
  const int KS = (N_ / NSPLIT) / 64;

  float va[2][8];
  ushort ub[2][8];

#pragma unroll
  for (int q = 0; q < 2; ++q) {
    const float* g = Abase + (size_t)(n0 + (nb0 + q * 4) * 8) * C_ + cA;
#pragma unroll
    for (int kk = 0; kk < 8; ++kk) va[q][kk] = g[(size_t)kk * C_];
  }
#pragma unroll
  for (int q = 0; q < 2; ++q) {
    const ushort* g = Bbase + (size_t)(n0 + (nb0 + q * 4) * 8) * KV_ + jg;
#pragma unroll
    for (int kk = 0; kk < 8; ++kk) ub[q][kk] = g[(size_t)kk * KV_];
  }

  for (int ks = 0; ks < KS; ++ks) {
    bfpack pa[2], pb[2];
#pragma unroll
    for (int q = 0; q < 2; ++q)
#pragma unroll
      for (int p = 0; p < 4; ++p) pa[q].u[p] = cvtpk(va[q][2 * p], va[q][2 * p + 1]);
#pragma unroll
    for (int q = 0; q < 2; ++q)
#pragma unroll
      for (int kk = 0; kk < 8; ++kk) pb[q].s[kk] = ub[q][kk];

    __builtin_amdgcn_s_barrier();

#pragma unroll
    for (int q = 0; q < 2; ++q) {
      const int nb = nb0 + q * 4;
      *(bf16x8*)(As + cA * 64 + ((nb ^ (cA & 7)) << 3)) = pa[q].v;
      *(bf16x8*)(Bs + jB * 64 + ((nb ^ (jB & 7)) << 3)) = pb[q].v;
    }

    if (ks + 1 < KS) {
      const int nb1 = n0 + (ks + 1) * 64;
#pragma unroll
      for (int q = 0; q < 2; ++q) {
        const float* g = Abase + (size_t)(nb1 + (nb0 + q * 4) * 8) * C_ + cA;
#pragma unroll
        for (int kk = 0; kk < 8; ++kk) va[q][kk] = g[(size_t)kk * C_];
      }
#pragma unroll
      for (int q = 0; q < 2; ++q) {
        const ushort* g = Bbase + (size_t)(nb1 + (nb0 + q * 4) * 8) * KV_ + jg;
#pragma unroll
        for (int kk = 0; kk < 8; ++kk) ub[q][kk] = g[(size_t)kk * KV_];
      }
    }

    asm volatile("s_waitcnt lgkmcnt(0)" ::: "memory");
    __builtin_amdgcn_sched_barrier(0);
    __builtin_amdgcn_s_barrier();

#pragma unroll
    for (int half = 0; half < 2; ++half) {
      const int kb = half * 4 + (l >> 4);
      bf16x8 af[2], bv[4];
#pragma unroll
      for (int fm = 0; fm < 2; ++fm) {
        const int i = wm * 32 + fm * 16 + lrow;
        af[fm] = *(const bf16x8*)(As + i * 64 + ((kb ^ (i & 7)) << 3));
      }
#pragma unroll
      for (int fn = 0; fn < 4; ++fn) {
        const int j = wn * 64 + fn * 16 + lrow;
        bv[fn] = *(const bf16x8*)(Bs + j * 64 + ((kb ^ (j & 7)) << 3));
      }
#pragma unroll
      for (int fm = 0; fm < 2; ++fm)
#pragma unroll
        for (int fn = 0; fn < 4; ++fn)
          acc[fm][fn] = __builtin_amdgcn_mfma_f32_16x16x32_bf16(af[fm], bv[fn],
                                                                acc[fm][fn], 0, 0, 0);
    }
  }
  f32x4* Pv4 = (f32x4*)P + ((size_t)(split * 32 + bh) * 2 + jh) * 4096;
#pragma unroll
  for (int fm = 0; fm < 2; ++fm)
#pragma unroll
    for (int fn = 0; fn < 4; ++fn) Pv4[(fm * 4 + fn) * 512 + t] = acc[fm][fn];
}

// ---------------------------------------------------------------------------
// Reduce NSPLIT fragment-native partials and un-swizzle into S[bh][128][240].
// ---------------------------------------------------------------------------
__global__ __launch_bounds__(256) void k_reduce_frag(const f32x4* __restrict__ P,
                                                     float* __restrict__ S) {
  const int bh = blockIdx.x;
  const int g = blockIdx.y * 256 + threadIdx.x;
  const int jh = g >> 12;
  const int rest = g & 4095;
  f32x4 a = P[((size_t)bh * 2 + jh) * 4096 + rest];
#pragma unroll
  for (int s = 1; s < NSPLIT; ++s) {
    f32x4 v = P[((size_t)(s * 32 + bh) * 2 + jh) * 4096 + rest];
    a.x += v.x; a.y += v.y; a.z += v.z; a.w += v.w;
  }
  const int v = rest >> 9, tt = rest & 511;
  const int fm = v >> 2, fn = v & 3;
  const int wv = tt >> 6, l = tt & 63;
  const int wm = wv >> 1, wn = wv & 1;
  const int i0 = wm * 32 + fm * 16 + (l >> 4) * 4;
  const int j = jh * 128 + wn * 64 + fn * 16 + (l & 15);
  if (j < DK) {
    float* sp = S + (size_t)bh * (DQ * DK) + (size_t)i0 * DK + j;
    sp[0] = a.x; sp[DK] = a.y; sp[2 * DK] = a.z; sp[3 * DK] = a.w;
  }
}

// ---------------------------------------------------------------------------
// f32 -> bf16 (RNE), 4 elems/thread
// ---------------------------------------------------------------------------
__global__ __launch_bounds__(256) void k_cvt(const float4* __restrict__ in,
                                             ushort4* __restrict__ out, int n4) {
  int i = blockIdx.x * 256 + threadIdx.x;
  if (i >= n4) return;
  float4 v = in[i];
  ushort4 o;
  o.x = f2bf(v.x); o.y = f2bf(v.y); o.z = f2bf(v.z); o.w = f2bf(v.w);
  out[i] = o;
}

// ===========================================================================
// Flat-batched f32 chain GEMMs (unchanged from R6).
// ===========================================================================
__global__ __launch_bounds__(256) void k_g1(const float* __restrict__ Wq,
                                            const float* __restrict__ S,
                                            float* __restrict__ U) {
  const int h = blockIdx.x, c0 = blockIdx.y * 64;
  const int b = blockIdx.z / 5, n0 = (blockIdx.z % 5) * 48;
  const float* A = Wq + (size_t)h * 16384;
  const float* Bp = S + (size_t)(b * 4 + h) * 30720 + n0;
  float* Cp = U + (size_t)(b * 4 + h) * 30720 + n0;
  __shared__ float Ast[16][65];
  __shared__ float Bst[16][49];
  const int t = threadIdx.x;
  const int mi = (t >> 4) * 4, nj = (t & 15) * 3;
  float acc[4][3] = {};
  for (int k0 = 0; k0 < 128; k0 += 16) {
    __syncthreads();
#pragma unroll
    for (int q = 0; q < 4; ++q) {
      int idx = t + q * 256, m = idx >> 4, k = idx & 15;
      Ast[k][m] = A[(size_t)(c0 + m) * 128 + k0 + k];
    }
#pragma unroll
    for (int q = 0; q < 3; ++q) {
      int idx = t + q * 256, k = idx / 48, n = idx % 48;
      Bst[k][n] = Bp[(size_t)(k0 + k) * 240 + n];
    }
    __syncthreads();
#pragma unroll
    for (int kk = 0; kk < 16; ++kk) {
      float a4[4], b3[3];
#pragma unroll
      for (int x = 0; x < 4; ++x) a4[x] = Ast[kk][mi + x];
#pragma unroll
      for (int y = 0; y < 3; ++y) b3[y] = Bst[kk][nj + y];
#pragma unroll
      for (int x = 0; x < 4; ++x)
#pragma unroll
        for (int y = 0; y < 3; ++y) acc[x][y] = fmaf(a4[x], b3[y], acc[x][y]);
    }
  }
#pragma unroll
  for (int x = 0; x < 4; ++x)
#pragma unroll
    for (int y = 0; y < 3; ++y)
      Cp[(size_t)(c0 + mi + x) * 240 + nj + y] = acc[x][y];
}

__global__ __launch_bounds__(256) void k_g2(const float* __restrict__ U,
                                            const float* __restrict__ Wk,
                                            float* __restrict__ SC) {
  const int m0 = blockIdx.x * 64, n0 = blockIdx.y * 48;
  __shared__ float Ast[16][65];
  __shared__ float Bst2[48][17];
  const int t = threadIdx.x;
  const int mi = (t >> 4) * 4, nj = (t & 15) * 3;
  float acc[4][3] = {};
  for (int k0 = 0; k0 < 240; k0 += 16) {
    __syncthreads();
#pragma unroll
    for (int q = 0; q < 4; ++q) {
      int idx = t + q * 256, m = idx >> 4, k = idx & 15;
      Ast[k][m] = U[(size_t)(m0 + m) * 240 + k0 + k];
    }
#pragma unroll
    for (int q = 0; q < 3; ++q) {
      int idx = t + q * 256, n = idx >> 4, kd = idx & 15;
      Bst2[n][kd] = Wk[(size_t)(n0 + n) * 240 + k0 + kd];
    }
    __syncthreads();
#pragma unroll
    for (int kk = 0; kk < 16; ++kk) {
      float a4[4], b3[3];
#pragma unroll
      for (int x = 0; x < 4; ++x) a4[x] = Ast[kk][mi + x];
#pragma unroll
      for (int y = 0; y < 3; ++y) b3[y] = Bst2[nj + y][kk];
#pragma unroll
      for (int x = 0; x < 4; ++x)
#pragma unroll
        for (int y = 0; y < 3; ++y) acc[x][y] = fmaf(a4[x], b3[y], acc[x][y]);
    }
  }
  const float scale = 0.0322748612183951f;
#pragma unroll
  for (int x = 0; x < 4; ++x)
#pragma unroll
    for (int y = 0; y < 3; ++y)
      SC[(size_t)(m0 + mi + x) * 240 + n0 + nj + y] = acc[x][y] * scale;
}

__global__ __launch_bounds__(256) void k_g3(const float* __restrict__ PR,
                                            const float* __restrict__ Wv,
                                            float* __restrict__ T) {
  const int m0 = blockIdx.x * 64, n0 = blockIdx.y * 48;
  __shared__ float Ast[16][65];
  __shared__ float Bst[16][49];
  const int t = threadIdx.x;
  const int mi = (t >> 4) * 4, nj = (t & 15) * 3;
  float acc[4][3] = {};
  for (int k0 = 0; k0 < 240; k0 += 16) {
    __syncthreads();
#pragma unroll
    for (int q = 0; q < 4; ++q) {
      int idx = t + q * 256, m = idx >> 4, k = idx & 15;
      Ast[k][m] = PR[(size_t)(m0 + m) * 240 + k0 + k];
    }
#pragma unroll
    for (int q = 0; q < 3; ++q) {
      int idx = t + q * 256, k = idx / 48, n = idx % 48;
      Bst[k][n] = Wv[(size_t)(k0 + k) * 240 + n0 + n];
    }
    __syncthreads();
#pragma unroll
    for (int kk = 0; kk < 16; ++kk) {
      float a4[4], b3[3];
#pragma unroll
      for (int x = 0; x < 4; ++x) a4[x] = Ast[kk][mi + x];
#pragma unroll
      for (int y = 0; y < 3; ++y) b3[y] = Bst[kk][nj + y];
#pragma unroll
      for (int x = 0; x < 4; ++x)
#pragma unroll
        for (int y = 0; y < 3; ++y) acc[x][y] = fmaf(a4[x], b3[y], acc[x][y]);
    }
  }
#pragma unroll
  for (int x = 0; x < 4; ++x)
#pragma unroll
    for (int y = 0; y < 3; ++y)
      T[(size_t)(m0 + mi + x) * 240 + n0 + nj + y] = acc[x][y];
}

__global__ __launch_bounds__(256) void k_g4(const float* __restrict__ Wo,
                                            const float* __restrict__ T,
                                            ushort* __restrict__ W3bf) {
  const int h = blockIdx.x, e0 = blockIdx.y * 64;
  const int b = blockIdx.z / 5, n0 = (blockIdx.z % 5) * 48;
  const float* Bp = T + (size_t)(b * 4 + h) * 30720 + n0;
  ushort* Cp = W3bf + (size_t)b * 491520 + h * 240 + n0;
  __shared__ float Ast[16][65];
  __shared__ float Bst[16][49];
  const int t = threadIdx.x;
  const int mi = (t >> 4) * 4, nj = (t & 15) * 3;
  float acc[4][3] = {};
  for (int k0 = 0; k0 < 128; k0 += 16) {
    __syncthreads();
#pragma unroll
    for (int q = 0; q < 4; ++q) {
      int idx = t + q * 256, m = idx >> 4, k = idx & 15;
      Ast[k][m] = Wo[(size_t)(e0 + m) * 512 + 4 * (k0 + k) + h];
    }
#pragma unroll
    for (int q = 0; q < 3; ++q) {
      int idx = t + q * 256, k = idx / 48, n = idx % 48;
      Bst[k][n] = Bp[(size_t)(k0 + k) * 240 + n];
    }
    __syncthreads();
#pragma unroll
    for (int kk = 0; kk < 16; ++kk) {
      float a4[4], b3[3];
#pragma unroll
      for (int x = 0; x < 4; ++x) a4[x] = Ast[kk][mi + x];
#pragma unroll
      for (int y = 0; y < 3; ++y) b3[y] = Bst[kk][nj + y];
#pragma unroll
      for (int x = 0; x < 4; ++x)
#pragma unroll
        for (int y = 0; y < 3; ++y) acc[x][y] = fmaf(a4[x], b3[y], acc[x][y]);
    }
  }
#pragma unroll
  for (int x = 0; x < 4; ++x)
#pragma unroll
    for (int y = 0; y < 3; ++y)
      Cp[(size_t)(e0 + mi + x) * 960 + nj + y] = f2bf(acc[x][y]);
}

// ---------------------------------------------------------------------------
// Stats + softmax (unchanged from R6).
// ---------------------------------------------------------------------------
__global__ __launch_bounds__(1024) void k_stats(const float* __restrict__ SC,
                                                float* __restrict__ stats) {
  const int bh = blockIdx.x;
  const float* s = SC + (size_t)bh * 30720;
  const int t = threadIdx.x;
  float sum = 0.f, sq = 0.f;
  for (int i = t; i < 30720; i += 1024) {
    float v = s[i];
    sum += v;
    sq = fmaf(v, v, sq);
  }
#pragma unroll
  for (int o = 32; o > 0; o >>= 1) {
    sum += __shfl_down(sum, o);
    sq += __shfl_down(sq, o);
  }
  __shared__ float s1[16], s2[16];
  if ((t & 63) == 0) { s1[t >> 6] = sum; s2[t >> 6] = sq; }
  __syncthreads();
  if (t == 0) {
    float ts = 0.f, tq = 0.f;
#pragma unroll
    for (int i = 0; i < 16; ++i) { ts += s1[i]; tq += s2[i]; }
    const float mu = ts * (1.f / 30720.f);
    const float var = tq * (1.f / 30720.f) - mu * mu;
    stats[bh * 2] = mu;
    stats[bh * 2 + 1] = rsqrtf(var + 1e-5f);
  }
}

__global__ __launch_bounds__(512) void k_softmax(const float* __restrict__ SC,
                                                 const float* __restrict__ stats,
                                                 float* __restrict__ PR) {
  const int bh = blockIdx.x;
  const float mu = stats[bh * 2], rstd = stats[bh * 2 + 1];
  const int wv = threadIdx.x >> 6, l = threadIdx.x & 63;
  const int row0 = blockIdx.y * 32 + wv * 4;
  const float* s = SC + (size_t)bh * 30720;
  float* p = PR + (size_t)bh * 30720;
#pragma unroll
  for (int r = 0; r < 4; ++r) {
    const float* srow = s + (size_t)(row0 + r) * 240;
    float* prow = p + (size_t)(row0 + r) * 240;
    float x0 = (srow[l] - mu) * rstd;
    float x1 = (srow[64 + l] - mu) * rstd;
    float x2 = (srow[128 + l] - mu) * rstd;
    float x3 = (l < 48) ? (srow[192 + l] - mu) * rstd : -1e30f;
    float m = fmaxf(fmaxf(x0, x1), fmaxf(x2, x3));
#pragma unroll
    for (int o = 32; o > 0; o >>= 1) m = fmaxf(m, __shfl_xor(m, o));
    float e0 = __expf(x0 - m), e1 = __expf(x1 - m), e2 = __expf(x2 - m);
    float e3 = (l < 48) ? __expf(x3 - m) : 0.f;
    float ss = e0 + e1 + e2 + e3;
#pragma unroll
    for (int o = 32; o > 0; o >>= 1) ss += __shfl_xor(ss, o);
    const float inv = 1.f / ss;
    prow[l] = e0 * inv;
    prow[64 + l] = e1 * inv;
    prow[128 + l] = e2 * inv;
    if (l < 48) prow[192 + l] = e3 * inv;
  }
}

// ---------------------------------------------------------------------------
// K3 (MFMA, conflict-free LDS): O1[b,n,e] = sum_g embaBF[b,n,g] * W3bf[b,e,g]
// 128x128 tile, BK=32, 4 waves (2x2), global_load_lds w=16, XCD swizzle.
// LDS layout change vs R6: each 16-row group stored in LANE-READ order —
// lane l stages global (row = l&15, kchunk = l>>4) to linear dest
// group*1024B + l*16B; fragment read = group*1024B + l*16B (64 consecutive
// 16B chunks per wave -> ZERO bank conflicts; same global footprint).
// ---------------------------------------------------------------------------
__global__ __launch_bounds__(256) void k3_mfma(const ushort* __restrict__ A,
                                               const ushort* __restrict__ Bw,
                                               float* __restrict__ C) {
  __shared__ ushort As[128 * 32];
  __shared__ ushort Bs[128 * 32];
  const int bid = blockIdx.x;
  const int swz = (bid & 7) * 128 + (bid >> 3);
  const int b = swz >> 7;
  const int rem = swz & 127;
  const int mt = rem >> 2, nt = rem & 3;
  const int t = threadIdx.x;
  const int w = t >> 6, l = t & 63;
  const int wr = w >> 1, wc = w & 1;

  const ushort* Ab = A + (size_t)b * N_ * KV_ + (size_t)mt * 128 * KV_;
  const ushort* Bb = Bw + (size_t)b * C_ * KV_ + (size_t)nt * 128 * KV_;

  const int r_l = l & 15;        // staging row within 16-row group
  const int c_l = (l >> 4) * 8;  // staging k-chunk (elems)

  f32x4 acc[4][4];
#pragma unroll
  for (int fm = 0; fm < 4; ++fm)
#pragma unroll
    for (int fn = 0; fn < 4; ++fn) acc[fm][fn] = (f32x4){0.f, 0.f, 0.f, 0.f};

  for (int k0 = 0; k0 < KV_; k0 += 32) {
#pragma unroll
    for (int inst = 0; inst < 2; ++inst) {
      const int gi = w * 2 + inst;
      const ushort* ga = Ab + (size_t)(gi * 16 + r_l) * KV_ + k0 + c_l;
      __builtin_amdgcn_global_load_lds((AS1 const uint32_t*)(uintptr_t)ga,
                                       (AS3 uint32_t*)(uintptr_t)(As + gi * 512),
                                       16, 0, 0);
      const ushort* gb = Bb + (size_t)(gi * 16 + r_l) * KV_ + k0 + c_l;
      __builtin_amdgcn_global_load_lds((AS1 const uint32_t*)(uintptr_t)gb,
                                       (AS3 uint32_t*)(uintptr_t)(Bs + gi * 512),
                                       16, 0, 0);
    }
    __syncthreads();
    bf16x8 af[4], bfr[4];
#pragma unroll
    for (int fm = 0; fm < 4; ++fm)
      af[fm] = *(const bf16x8*)(As + (wr * 4 + fm) * 512 + l * 8);
#pragma unroll
    for (int fn = 0; fn < 4; ++fn)
      bfr[fn] = *(const bf16x8*)(Bs + (wc * 4 + fn) * 512 + l * 8);
#pragma unroll
    for (int fm = 0; fm < 4; ++fm)
#pragma unroll
      for (int fn = 0; fn < 4; ++fn)
        acc[fm][fn] = __builtin_amdgcn_mfma_f32_16x16x32_bf16(af[fm], bfr[fn],
                                                              acc[fm][fn], 0, 0, 0);
    __syncthreads();
  }

  float* Cb = C + (size_t)b * N_ * C_ + ((size_t)mt * 128) * C_ + nt * 128;
  const int col = wc * 64 + (l & 15);
  const int rbase = wr * 64 + (l >> 4) * 4;
#pragma unroll
  for (int fm = 0; fm < 4; ++fm)
#pragma unroll
    for (int fn = 0; fn < 4; ++fn)
#pragma unroll
      for (int r = 0; r < 4; ++r)
        Cb[(size_t)(rbase + fm * 16 + r) * C_ + col + fn * 16] = acc[fm][fn][r];
}

// ---------------------------------------------------------------------------
// Memory plan (ws 78,643,200 B + d_out as scratch) — identical to R6:
//   d_out [0, 33554432)     P frag-partials -- dead before k3 overwrites
//   ws [0, 62914560)        embaBF (bf16), written FIRST
//   ws [62914560, 66846720) S (f32) -> then T (f32, after g1)
//   ws [66846720, 70778880) U (f32); stats overlays after g2; W3bf later
//   ws [70778880, 74711040) SC (f32) } W3bf (bf16) overlays U+SC in g4
//   ws [74711040, 78643200) PR (f32)
// ---------------------------------------------------------------------------
extern "C" void kernel_launch(void* const* d_in, const int* in_sizes, int n_in,
                              void* d_out, int out_size, void* d_ws, size_t ws_size,
                              hipStream_t stream) {
  const float* emb1 = (const float*)d_in[0];
  const float* emba = (const float*)d_in[1];
  const float* Wq   = (const float*)d_in[2];
  const float* Wk   = (const float*)d_in[3];
  const float* Wv   = (const float*)d_in[4];
  const float* Wo   = (const float*)d_in[5];
  float* out = (float*)d_out;
  char* ws = (char*)d_ws;

  ushort* embaBF = (ushort*)(ws);
  float*  S      = (float*)(ws + 62914560);
  float*  T      = (float*)(ws + 62914560);
  float*  U      = (float*)(ws + 66846720);
  ushort* W3bf   = (ushort*)(ws + 66846720);
  float*  SCb    = (float*)(ws + 70778880);
  float*  PRb    = (float*)(ws + 74711040);
  float*  P      = out;
  float*  stats  = (float*)(ws + 66846720);  // U region, dead after g2

  // 1) emb_all -> bf16 (feeds k1's B-gather and k3's A)
  k_cvt<<<30720, 256, 0, stream>>>((const float4*)emba, (ushort4*)embaBF, 7864320);

  // 2) S partials (MFMA, 2 blocks/CU) + reduce/unswizzle
  k1_mfma<<<dim3(32, NSPLIT, 2), 512, 0, stream>>>(emb1, embaBF, P);
  k_reduce_frag<<<dim3(32, 32), 256, 0, stream>>>((const f32x4*)P, S);

  // 3) chain (flat-batched f32 GEMMs + stats + softmax)
  k_g1<<<dim3(4, 2, 40), 256, 0, stream>>>(Wq, S, U);
  k_g2<<<dim3(64, 5), 256, 0, stream>>>(U, Wk, SCb);
  k_stats<<<32, 1024, 0, stream>>>(SCb, stats);
  k_softmax<<<dim3(32, 4), 512, 0, stream>>>(SCb, stats, PRb);
  k_g3<<<dim3(64, 5), 256, 0, stream>>>(PRb, Wv, T);
  k_g4<<<dim3(4, 8, 40), 256, 0, stream>>>(Wo, T, W3bf);

  // 4) O1[b] = embaBF[b] @ W3bf[b]^T  (MFMA, conflict-free, XCD-swizzled)
  k3_mfma<<<1024, 256, 0, stream>>>(embaBF, W3bf, out);
}

// Round 10
// 254.883 us; speedup vs baseline: 1.0747x; 1.0091x over previous
//
#include <hip/hip_runtime.h>
#include <cstdint>
#include <cstddef>

#define B_ 8
#define N_ 4096
#define C_ 512
#define KV_ 960
#define DQ 128
#define DK 240
#define NSPLIT 8   // split-K over n for k1; grid 32*8*2 = 512 blocks = 2/CU

typedef __attribute__((ext_vector_type(8))) short bf16x8;
typedef __attribute__((ext_vector_type(4))) float f32x4;
#define AS1 __attribute__((address_space(1)))
#define AS3 __attribute__((address_space(3)))

__device__ __forceinline__ ushort f2bf(float f) {
  uint32_t u = __float_as_uint(f);
  u += 0x7FFFu + ((u >> 16) & 1u);  // RNE
  return (ushort)(u >> 16);
}

__device__ __forceinline__ uint32_t cvtpk(float lo, float hi) {
  uint32_t r;
  asm("v_cvt_pk_bf16_f32 %0, %1, %2" : "=v"(r) : "v"(lo), "v"(hi));
  return r;
}

union bfpack {
  uint32_t u[4];
  ushort s[8];
  bf16x8 v;
};

// ---------------------------------------------------------------------------
// K1 (MFMA, 2 blocks/CU, gather-staged): partial
//   S[b,h,i,j] = sum_{n in split} emb1[b,n,h*128+i] * embaBF[b,n,h*240+j]
// (R6-proven version, unchanged)
// ---------------------------------------------------------------------------
__global__ __launch_bounds__(512) void k1_mfma(const float* __restrict__ emb1,
                                               const ushort* __restrict__ embaBF,
                                               float* __restrict__ P) {
  __shared__ ushort As[128 * 64];
  __shared__ ushort Bs[128 * 64];
  const int bh = blockIdx.x;
  const int split = blockIdx.y;
  const int jh = blockIdx.z;
  const int b = bh >> 2, h = bh & 3;
  const int t = threadIdx.x;
  const int w = t >> 6, l = t & 63;
  const int wm = w >> 1, wn = w & 1;

  const float* Abase = emb1 + (size_t)b * N_ * C_ + h * DQ;
  const ushort* Bbase = embaBF + (size_t)b * N_ * KV_;

  const int cA = t & 127;
  const int jB = t & 127;
  const int nb0 = t >> 7;
  int jl = jh * 128 + jB;
  if (jl > DK - 1) jl = DK - 1;
  const int jg = h * DK + jl;

  f32x4 acc[2][4];
#pragma unroll
  for (int fm = 0; fm < 2; ++fm)
#pragma unroll
    for (int fn = 0; fn < 4; ++fn) acc[fm][fn] = (f32x4){0.f, 0.f, 0.f, 0.f};

  const int n0 = split * (N_ / NSPLIT);
  const int lrow = l & 15;
  const int KS = (N_ / NSPLIT) / 64;

  float va[2][8];
  ushort ub[2][8];

#pragma unroll
  for (int q = 0; q < 2; ++q) {
    const float* g = Abase + (size_t)(n0 + (nb0 + q * 4) * 8) * C_ + cA;
#pragma unroll
    for (int kk = 0; kk < 8; ++kk) va[q][kk] = g[(size_t)kk * C_];
  }
#pragma unroll
  for (int q = 0; q < 2; ++q) {
    const ushort* g = Bbase + (size_t)(n0 + (nb0 + q * 4) * 8) * KV_ + jg;
#pragma unroll
    for (int kk = 0; kk < 8; ++kk) ub[q][kk] = g[(size_t)kk * KV_];
  }

  for (int ks = 0; ks < KS; ++ks) {
    bfpack pa[2], pb[2];
#pragma unroll
    for (int q = 0; q < 2; ++q)
#pragma unroll
      for (int p = 0; p < 4; ++p) pa[q].u[p] = cvtpk(va[q][2 * p], va[q][2 * p + 1]);
#pragma unroll
    for (int q = 0; q < 2; ++q)
#pragma unroll
      for (int kk = 0; kk < 8; ++kk) pb[q].s[kk] = ub[q][kk];

    __builtin_amdgcn_s_barrier();

#pragma unroll
    for (int q = 0; q < 2; ++q) {
      const int nb = nb0 + q * 4;
      *(bf16x8*)(As + cA * 64 + ((nb ^ (cA & 7)) << 3)) = pa[q].v;
      *(bf16x8*)(Bs + jB * 64 + ((nb ^ (jB & 7)) << 3)) = pb[q].v;
    }

    if (ks + 1 < KS) {
      const int nb1 = n0 + (ks + 1) * 64;
#pragma unroll
      for (int q = 0; q < 2; ++q) {
        const float* g = Abase + (size_t)(nb1 + (nb0 + q * 4) * 8) * C_ + cA;
#pragma unroll
        for (int kk = 0; kk < 8; ++kk) va[q][kk] = g[(size_t)kk * C_];
      }
#pragma unroll
      for (int q = 0; q < 2; ++q) {
        const ushort* g = Bbase + (size_t)(nb1 + (nb0 + q * 4) * 8) * KV_ + jg;
#pragma unroll
        for (int kk = 0; kk < 8; ++kk) ub[q][kk] = g[(size_t)kk * KV_];
      }
    }

    asm volatile("s_waitcnt lgkmcnt(0)" ::: "memory");
    __builtin_amdgcn_sched_barrier(0);
    __builtin_amdgcn_s_barrier();

#pragma unroll
    for (int half = 0; half < 2; ++half) {
      const int kb = half * 4 + (l >> 4);
      bf16x8 af[2], bv[4];
#pragma unroll
      for (int fm = 0; fm < 2; ++fm) {
        const int i = wm * 32 + fm * 16 + lrow;
        af[fm] = *(const bf16x8*)(As + i * 64 + ((kb ^ (i & 7)) << 3));
      }
#pragma unroll
      for (int fn = 0; fn < 4; ++fn) {
        const int j = wn * 64 + fn * 16 + lrow;
        bv[fn] = *(const bf16x8*)(Bs + j * 64 + ((kb ^ (j & 7)) << 3));
      }
#pragma unroll
      for (int fm = 0; fm < 2; ++fm)
#pragma unroll
        for (int fn = 0; fn < 4; ++fn)
          acc[fm][fn] = __builtin_amdgcn_mfma_f32_16x16x32_bf16(af[fm], bv[fn],
                                                                acc[fm][fn], 0, 0, 0);
    }
  }
  f32x4* Pv4 = (f32x4*)P + ((size_t)(split * 32 + bh) * 2 + jh) * 4096;
#pragma unroll
  for (int fm = 0; fm < 2; ++fm)
#pragma unroll
    for (int fn = 0; fn < 4; ++fn) Pv4[(fm * 4 + fn) * 512 + t] = acc[fm][fn];
}

// ---------------------------------------------------------------------------
// Reduce NSPLIT fragment-native partials and un-swizzle into S[bh][128][240].
// ---------------------------------------------------------------------------
__global__ __launch_bounds__(256) void k_reduce_frag(const f32x4* __restrict__ P,
                                                     float* __restrict__ S) {
  const int bh = blockIdx.x;
  const int g = blockIdx.y * 256 + threadIdx.x;
  const int jh = g >> 12;
  const int rest = g & 4095;
  f32x4 a = P[((size_t)bh * 2 + jh) * 4096 + rest];
#pragma unroll
  for (int s = 1; s < NSPLIT; ++s) {
    f32x4 v = P[((size_t)(s * 32 + bh) * 2 + jh) * 4096 + rest];
    a.x += v.x; a.y += v.y; a.z += v.z; a.w += v.w;
  }
  const int v = rest >> 9, tt = rest & 511;
  const int fm = v >> 2, fn = v & 3;
  const int wv = tt >> 6, l = tt & 63;
  const int wm = wv >> 1, wn = wv & 1;
  const int i0 = wm * 32 + fm * 16 + (l >> 4) * 4;
  const int j = jh * 128 + wn * 64 + fn * 16 + (l & 15);
  if (j < DK) {
    float* sp = S + (size_t)bh * (DQ * DK) + (size_t)i0 * DK + j;
    sp[0] = a.x; sp[DK] = a.y; sp[2 * DK] = a.z; sp[3 * DK] = a.w;
  }
}

// ---------------------------------------------------------------------------
// f32 -> bf16 (RNE), 4 elems/thread
// ---------------------------------------------------------------------------
__global__ __launch_bounds__(256) void k_cvt(const float4* __restrict__ in,
                                             ushort4* __restrict__ out, int n4) {
  int i = blockIdx.x * 256 + threadIdx.x;
  if (i >= n4) return;
  float4 v = in[i];
  ushort4 o;
  o.x = f2bf(v.x); o.y = f2bf(v.y); o.z = f2bf(v.z); o.w = f2bf(v.w);
  out[i] = o;
}

// ===========================================================================
// Flat-batched f32 chain GEMMs (unchanged from R6).
// ===========================================================================
__global__ __launch_bounds__(256) void k_g1(const float* __restrict__ Wq,
                                            const float* __restrict__ S,
                                            float* __restrict__ U) {
  const int h = blockIdx.x, c0 = blockIdx.y * 64;
  const int b = blockIdx.z / 5, n0 = (blockIdx.z % 5) * 48;
  const float* A = Wq + (size_t)h * 16384;
  const float* Bp = S + (size_t)(b * 4 + h) * 30720 + n0;
  float* Cp = U + (size_t)(b * 4 + h) * 30720 + n0;
  __shared__ float Ast[16][65];
  __shared__ float Bst[16][49];
  const int t = threadIdx.x;
  const int mi = (t >> 4) * 4, nj = (t & 15) * 3;
  float acc[4][3] = {};
  for (int k0 = 0; k0 < 128; k0 += 16) {
    __syncthreads();
#pragma unroll
    for (int q = 0; q < 4; ++q) {
      int idx = t + q * 256, m = idx >> 4, k = idx & 15;
      Ast[k][m] = A[(size_t)(c0 + m) * 128 + k0 + k];
    }
#pragma unroll
    for (int q = 0; q < 3; ++q) {
      int idx = t + q * 256, k = idx / 48, n = idx % 48;
      Bst[k][n] = Bp[(size_t)(k0 + k) * 240 + n];
    }
    __syncthreads();
#pragma unroll
    for (int kk = 0; kk < 16; ++kk) {
      float a4[4], b3[3];
#pragma unroll
      for (int x = 0; x < 4; ++x) a4[x] = Ast[kk][mi + x];
#pragma unroll
      for (int y = 0; y < 3; ++y) b3[y] = Bst[kk][nj + y];
#pragma unroll
      for (int x = 0; x < 4; ++x)
#pragma unroll
        for (int y = 0; y < 3; ++y) acc[x][y] = fmaf(a4[x], b3[y], acc[x][y]);
    }
  }
#pragma unroll
  for (int x = 0; x < 4; ++x)
#pragma unroll
    for (int y = 0; y < 3; ++y)
      Cp[(size_t)(c0 + mi + x) * 240 + nj + y] = acc[x][y];
}

__global__ __launch_bounds__(256) void k_g2(const float* __restrict__ U,
                                            const float* __restrict__ Wk,
                                            float* __restrict__ SC) {
  const int m0 = blockIdx.x * 64, n0 = blockIdx.y * 48;
  __shared__ float Ast[16][65];
  __shared__ float Bst2[48][17];
  const int t = threadIdx.x;
  const int mi = (t >> 4) * 4, nj = (t & 15) * 3;
  float acc[4][3] = {};
  for (int k0 = 0; k0 < 240; k0 += 16) {
    __syncthreads();
#pragma unroll
    for (int q = 0; q < 4; ++q) {
      int idx = t + q * 256, m = idx >> 4, k = idx & 15;
      Ast[k][m] = U[(size_t)(m0 + m) * 240 + k0 + k];
    }
#pragma unroll
    for (int q = 0; q < 3; ++q) {
      int idx = t + q * 256, n = idx >> 4, kd = idx & 15;
      Bst2[n][kd] = Wk[(size_t)(n0 + n) * 240 + k0 + kd];
    }
    __syncthreads();
#pragma unroll
    for (int kk = 0; kk < 16; ++kk) {
      float a4[4], b3[3];
#pragma unroll
      for (int x = 0; x < 4; ++x) a4[x] = Ast[kk][mi + x];
#pragma unroll
      for (int y = 0; y < 3; ++y) b3[y] = Bst2[nj + y][kk];
#pragma unroll
      for (int x = 0; x < 4; ++x)
#pragma unroll
        for (int y = 0; y < 3; ++y) acc[x][y] = fmaf(a4[x], b3[y], acc[x][y]);
    }
  }
  const float scale = 0.0322748612183951f;
#pragma unroll
  for (int x = 0; x < 4; ++x)
#pragma unroll
    for (int y = 0; y < 3; ++y)
      SC[(size_t)(m0 + mi + x) * 240 + n0 + nj + y] = acc[x][y] * scale;
}

__global__ __launch_bounds__(256) void k_g3(const float* __restrict__ PR,
                                            const float* __restrict__ Wv,
                                            float* __restrict__ T) {
  const int m0 = blockIdx.x * 64, n0 = blockIdx.y * 48;
  __shared__ float Ast[16][65];
  __shared__ float Bst[16][49];
  const int t = threadIdx.x;
  const int mi = (t >> 4) * 4, nj = (t & 15) * 3;
  float acc[4][3] = {};
  for (int k0 = 0; k0 < 240; k0 += 16) {
    __syncthreads();
#pragma unroll
    for (int q = 0; q < 4; ++q) {
      int idx = t + q * 256, m = idx >> 4, k = idx & 15;
      Ast[k][m] = PR[(size_t)(m0 + m) * 240 + k0 + k];
    }
#pragma unroll
    for (int q = 0; q < 3; ++q) {
      int idx = t + q * 256, k = idx / 48, n = idx % 48;
      Bst[k][n] = Wv[(size_t)(k0 + k) * 240 + n0 + n];
    }
    __syncthreads();
#pragma unroll
    for (int kk = 0; kk < 16; ++kk) {
      float a4[4], b3[3];
#pragma unroll
      for (int x = 0; x < 4; ++x) a4[x] = Ast[kk][mi + x];
#pragma unroll
      for (int y = 0; y < 3; ++y) b3[y] = Bst[kk][nj + y];
#pragma unroll
      for (int x = 0; x < 4; ++x)
#pragma unroll
        for (int y = 0; y < 3; ++y) acc[x][y] = fmaf(a4[x], b3[y], acc[x][y]);
    }
  }
#pragma unroll
  for (int x = 0; x < 4; ++x)
#pragma unroll
    for (int y = 0; y < 3; ++y)
      T[(size_t)(m0 + mi + x) * 240 + n0 + nj + y] = acc[x][y];
}

__global__ __launch_bounds__(256) void k_g4(const float* __restrict__ Wo,
                                            const float* __restrict__ T,
                                            ushort* __restrict__ W3bf) {
  const int h = blockIdx.x, e0 = blockIdx.y * 64;
  const int b = blockIdx.z / 5, n0 = (blockIdx.z % 5) * 48;
  const float* Bp = T + (size_t)(b * 4 + h) * 30720 + n0;
  ushort* Cp = W3bf + (size_t)b * 491520 + h * 240 + n0;
  __shared__ float Ast[16][65];
  __shared__ float Bst[16][49];
  const int t = threadIdx.x;
  const int mi = (t >> 4) * 4, nj = (t & 15) * 3;
  float acc[4][3] = {};
  for (int k0 = 0; k0 < 128; k0 += 16) {
    __syncthreads();
#pragma unroll
    for (int q = 0; q < 4; ++q) {
      int idx = t + q * 256, m = idx >> 4, k = idx & 15;
      Ast[k][m] = Wo[(size_t)(e0 + m) * 512 + 4 * (k0 + k) + h];
    }
#pragma unroll
    for (int q = 0; q < 3; ++q) {
      int idx = t + q * 256, k = idx / 48, n = idx % 48;
      Bst[k][n] = Bp[(size_t)(k0 + k) * 240 + n];
    }
    __syncthreads();
#pragma unroll
    for (int kk = 0; kk < 16; ++kk) {
      float a4[4], b3[3];
#pragma unroll
      for (int x = 0; x < 4; ++x) a4[x] = Ast[kk][mi + x];
#pragma unroll
      for (int y = 0; y < 3; ++y) b3[y] = Bst[kk][nj + y];
#pragma unroll
      for (int x = 0; x < 4; ++x)
#pragma unroll
        for (int y = 0; y < 3; ++y) acc[x][y] = fmaf(a4[x], b3[y], acc[x][y]);
    }
  }
#pragma unroll
  for (int x = 0; x < 4; ++x)
#pragma unroll
    for (int y = 0; y < 3; ++y)
      Cp[(size_t)(e0 + mi + x) * 960 + nj + y] = f2bf(acc[x][y]);
}

// ---------------------------------------------------------------------------
// Stats + softmax (unchanged from R6).
// ---------------------------------------------------------------------------
__global__ __launch_bounds__(1024) void k_stats(const float* __restrict__ SC,
                                                float* __restrict__ stats) {
  const int bh = blockIdx.x;
  const float* s = SC + (size_t)bh * 30720;
  const int t = threadIdx.x;
  float sum = 0.f, sq = 0.f;
  for (int i = t; i < 30720; i += 1024) {
    float v = s[i];
    sum += v;
    sq = fmaf(v, v, sq);
  }
#pragma unroll
  for (int o = 32; o > 0; o >>= 1) {
    sum += __shfl_down(sum, o);
    sq += __shfl_down(sq, o);
  }
  __shared__ float s1[16], s2[16];
  if ((t & 63) == 0) { s1[t >> 6] = sum; s2[t >> 6] = sq; }
  __syncthreads();
  if (t == 0) {
    float ts = 0.f, tq = 0.f;
#pragma unroll
    for (int i = 0; i < 16; ++i) { ts += s1[i]; tq += s2[i]; }
    const float mu = ts * (1.f / 30720.f);
    const float var = tq * (1.f / 30720.f) - mu * mu;
    stats[bh * 2] = mu;
    stats[bh * 2 + 1] = rsqrtf(var + 1e-5f);
  }
}

__global__ __launch_bounds__(512) void k_softmax(const float* __restrict__ SC,
                                                 const float* __restrict__ stats,
                                                 float* __restrict__ PR) {
  const int bh = blockIdx.x;
  const float mu = stats[bh * 2], rstd = stats[bh * 2 + 1];
  const int wv = threadIdx.x >> 6, l = threadIdx.x & 63;
  const int row0 = blockIdx.y * 32 + wv * 4;
  const float* s = SC + (size_t)bh * 30720;
  float* p = PR + (size_t)bh * 30720;
#pragma unroll
  for (int r = 0; r < 4; ++r) {
    const float* srow = s + (size_t)(row0 + r) * 240;
    float* prow = p + (size_t)(row0 + r) * 240;
    float x0 = (srow[l] - mu) * rstd;
    float x1 = (srow[64 + l] - mu) * rstd;
    float x2 = (srow[128 + l] - mu) * rstd;
    float x3 = (l < 48) ? (srow[192 + l] - mu) * rstd : -1e30f;
    float m = fmaxf(fmaxf(x0, x1), fmaxf(x2, x3));
#pragma unroll
    for (int o = 32; o > 0; o >>= 1) m = fmaxf(m, __shfl_xor(m, o));
    float e0 = __expf(x0 - m), e1 = __expf(x1 - m), e2 = __expf(x2 - m);
    float e3 = (l < 48) ? __expf(x3 - m) : 0.f;
    float ss = e0 + e1 + e2 + e3;
#pragma unroll
    for (int o = 32; o > 0; o >>= 1) ss += __shfl_xor(ss, o);
    const float inv = 1.f / ss;
    prow[l] = e0 * inv;
    prow[64 + l] = e1 * inv;
    prow[128 + l] = e2 * inv;
    if (l < 48) prow[192 + l] = e3 * inv;
  }
}

// ---------------------------------------------------------------------------
// K3 (MFMA, double-buffered T3-minimum pipeline, conflict-free LDS):
//   O1[b,n,e] = sum_g embaBF[b,n,g] * W3bf[b,e,g]
// 128x128 tile, BK=32, 4 waves (2x2), XCD swizzle. Per K-step:
//   STAGE(next -> buf^1) | ds_read+MFMA on buf | vmcnt(0) | s_barrier
// Loads for tile t+1 fly under tile t's compute; one barrier per step.
// LDS 2 x (8KB A + 8KB B) = 32KB. Lane-read-order groups: zero conflicts.
// ---------------------------------------------------------------------------
__global__ __launch_bounds__(256) void k3_mfma(const ushort* __restrict__ A,
                                               const ushort* __restrict__ Bw,
                                               float* __restrict__ C) {
  __shared__ ushort LDSu[2][8192];  // [buf][As 4096 | Bs 4096]
  const int bid = blockIdx.x;
  const int swz = (bid & 7) * 128 + (bid >> 3);
  const int b = swz >> 7;
  const int rem = swz & 127;
  const int mt = rem >> 2, nt = rem & 3;
  const int t = threadIdx.x;
  const int w = t >> 6, l = t & 63;
  const int wr = w >> 1, wc = w & 1;

  const ushort* Ab = A + (size_t)b * N_ * KV_ + (size_t)mt * 128 * KV_;
  const ushort* Bb = Bw + (size_t)b * C_ * KV_ + (size_t)nt * 128 * KV_;

  const int r_l = l & 15;        // staging row within 16-row group
  const int c_l = (l >> 4) * 8;  // staging k-chunk (elems)

#define K3STAGE(k0, bf)                                                        \
  do {                                                                         \
    _Pragma("unroll") for (int inst = 0; inst < 2; ++inst) {                   \
      const int gi = w * 2 + inst;                                             \
      const ushort* ga = Ab + (size_t)(gi * 16 + r_l) * KV_ + (k0) + c_l;      \
      __builtin_amdgcn_global_load_lds(                                        \
          (AS1 const uint32_t*)(uintptr_t)ga,                                  \
          (AS3 uint32_t*)(uintptr_t)(&LDSu[bf][0] + gi * 512), 16, 0, 0);      \
      const ushort* gb = Bb + (size_t)(gi * 16 + r_l) * KV_ + (k0) + c_l;      \
      __builtin_amdgcn_global_load_lds(                                        \
          (AS1 const uint32_t*)(uintptr_t)gb,                                  \
          (AS3 uint32_t*)(uintptr_t)(&LDSu[bf][4096] + gi * 512), 16, 0, 0);   \
    }                                                                          \
  } while (0)

  f32x4 acc[4][4];
#pragma unroll
  for (int fm = 0; fm < 4; ++fm)
#pragma unroll
    for (int fn = 0; fn < 4; ++fn) acc[fm][fn] = (f32x4){0.f, 0.f, 0.f, 0.f};

  // prologue: tile 0 into buf 0
  K3STAGE(0, 0);
  asm volatile("s_waitcnt vmcnt(0)" ::: "memory");
  __builtin_amdgcn_sched_barrier(0);
  __builtin_amdgcn_s_barrier();

  const int NK = KV_ / 32;  // 30
  for (int ks = 0; ks < NK; ++ks) {
    const int buf = ks & 1;
    if (ks + 1 < NK) {
      if (buf == 0) K3STAGE((ks + 1) * 32, 1);
      else          K3STAGE((ks + 1) * 32, 0);
    }
    bf16x8 af[4], bfr[4];
#pragma unroll
    for (int fm = 0; fm < 4; ++fm)
      af[fm] = *(const bf16x8*)(&LDSu[buf][0] + (wr * 4 + fm) * 512 + l * 8);
#pragma unroll
    for (int fn = 0; fn < 4; ++fn)
      bfr[fn] = *(const bf16x8*)(&LDSu[buf][4096] + (wc * 4 + fn) * 512 + l * 8);
#pragma unroll
    for (int fm = 0; fm < 4; ++fm)
#pragma unroll
      for (int fn = 0; fn < 4; ++fn)
        acc[fm][fn] = __builtin_amdgcn_mfma_f32_16x16x32_bf16(af[fm], bfr[fn],
                                                              acc[fm][fn], 0, 0, 0);
    asm volatile("s_waitcnt vmcnt(0)" ::: "memory");
    __builtin_amdgcn_sched_barrier(0);
    __builtin_amdgcn_s_barrier();
  }
#undef K3STAGE

  float* Cb = C + (size_t)b * N_ * C_ + ((size_t)mt * 128) * C_ + nt * 128;
  const int col = wc * 64 + (l & 15);
  const int rbase = wr * 64 + (l >> 4) * 4;
#pragma unroll
  for (int fm = 0; fm < 4; ++fm)
#pragma unroll
    for (int fn = 0; fn < 4; ++fn)
#pragma unroll
      for (int r = 0; r < 4; ++r)
        Cb[(size_t)(rbase + fm * 16 + r) * C_ + col + fn * 16] = acc[fm][fn][r];
}

// ---------------------------------------------------------------------------
// Memory plan (ws 78,643,200 B + d_out as scratch) — identical to R6/R9:
//   d_out [0, 33554432)     P frag-partials -- dead before k3 overwrites
//   ws [0, 62914560)        embaBF (bf16), written FIRST
//   ws [62914560, 66846720) S (f32) -> then T (f32, after g1)
//   ws [66846720, 70778880) U (f32); stats overlays after g2; W3bf later
//   ws [70778880, 74711040) SC (f32) } W3bf (bf16) overlays U+SC in g4
//   ws [74711040, 78643200) PR (f32)
// ---------------------------------------------------------------------------
extern "C" void kernel_launch(void* const* d_in, const int* in_sizes, int n_in,
                              void* d_out, int out_size, void* d_ws, size_t ws_size,
                              hipStream_t stream) {
  const float* emb1 = (const float*)d_in[0];
  const float* emba = (const float*)d_in[1];
  const float* Wq   = (const float*)d_in[2];
  const float* Wk   = (const float*)d_in[3];
  const float* Wv   = (const float*)d_in[4];
  const float* Wo   = (const float*)d_in[5];
  float* out = (float*)d_out;
  char* ws = (char*)d_ws;

  ushort* embaBF = (ushort*)(ws);
  float*  S      = (float*)(ws + 62914560);
  float*  T      = (float*)(ws + 62914560);
  float*  U      = (float*)(ws + 66846720);
  ushort* W3bf   = (ushort*)(ws + 66846720);
  float*  SCb    = (float*)(ws + 70778880);
  float*  PRb    = (float*)(ws + 74711040);
  float*  P      = out;
  float*  stats  = (float*)(ws + 66846720);  // U region, dead after g2

  // 1) emb_all -> bf16 (feeds k1's B-gather and k3's A)
  k_cvt<<<30720, 256, 0, stream>>>((const float4*)emba, (ushort4*)embaBF, 7864320);

  // 2) S partials (MFMA, 2 blocks/CU) + reduce/unswizzle
  k1_mfma<<<dim3(32, NSPLIT, 2), 512, 0, stream>>>(emb1, embaBF, P);
  k_reduce_frag<<<dim3(32, 32), 256, 0, stream>>>((const f32x4*)P, S);

  // 3) chain (flat-batched f32 GEMMs + stats + softmax)
  k_g1<<<dim3(4, 2, 40), 256, 0, stream>>>(Wq, S, U);
  k_g2<<<dim3(64, 5), 256, 0, stream>>>(U, Wk, SCb);
  k_stats<<<32, 1024, 0, stream>>>(SCb, stats);
  k_softmax<<<dim3(32, 4), 512, 0, stream>>>(SCb, stats, PRb);
  k_g3<<<dim3(64, 5), 256, 0, stream>>>(PRb, Wv, T);
  k_g4<<<dim3(4, 8, 40), 256, 0, stream>>>(Wo, T, W3bf);

  // 4) O1[b] = embaBF[b] @ W3bf[b]^T  (MFMA, pipelined, XCD-swizzled)
  k3_mfma<<<1024, 256, 0, stream>>>(embaBF, W3bf, out);
}

// Round 11
// 244.152 us; speedup vs baseline: 1.1219x; 1.0440x over previous
//
#include <hip/hip_runtime.h>
#include <cstdint>
#include <cstddef>

#define B_ 8
#define N_ 4096
#define C_ 512
#define KV_ 960
#define DQ 128
#define DK 240
#define NSPLIT 16  // split-K over n for k1; grid 32*16*2 = 1024 blocks = 4/CU

typedef __attribute__((ext_vector_type(8))) short bf16x8;
typedef __attribute__((ext_vector_type(4))) float f32x4;
#define AS1 __attribute__((address_space(1)))
#define AS3 __attribute__((address_space(3)))

__device__ __forceinline__ ushort f2bf(float f) {
  uint32_t u = __float_as_uint(f);
  u += 0x7FFFu + ((u >> 16) & 1u);  // RNE
  return (ushort)(u >> 16);
}

__device__ __forceinline__ uint32_t cvtpk(float lo, float hi) {
  uint32_t r;
  asm("v_cvt_pk_bf16_f32 %0, %1, %2" : "=v"(r) : "v"(lo), "v"(hi));
  return r;
}

union bfpack {
  uint32_t u[4];
  ushort s[8];
  bf16x8 v;
};

// ---------------------------------------------------------------------------
// K1 (MFMA, gather-staged, now 4 blocks/CU): partial
//   S[b,h,i,j] = sum_{n in split} emb1[b,n,h*128+i] * embaBF[b,n,h*240+j]
// (R6-proven structure; only NSPLIT raised 8->16 for occupancy)
// ---------------------------------------------------------------------------
__global__ __launch_bounds__(512) void k1_mfma(const float* __restrict__ emb1,
                                               const ushort* __restrict__ embaBF,
                                               float* __restrict__ P) {
  __shared__ ushort As[128 * 64];
  __shared__ ushort Bs[128 * 64];
  const int bh = blockIdx.x;
  const int split = blockIdx.y;
  const int jh = blockIdx.z;
  const int b = bh >> 2, h = bh & 3;
  const int t = threadIdx.x;
  const int w = t >> 6, l = t & 63;
  const int wm = w >> 1, wn = w & 1;

  const float* Abase = emb1 + (size_t)b * N_ * C_ + h * DQ;
  const ushort* Bbase = embaBF + (size_t)b * N_ * KV_;

  const int cA = t & 127;
  const int jB = t & 127;
  const int nb0 = t >> 7;
  int jl = jh * 128 + jB;
  if (jl > DK - 1) jl = DK - 1;
  const int jg = h * DK + jl;

  f32x4 acc[2][4];
#pragma unroll
  for (int fm = 0; fm < 2; ++fm)
#pragma unroll
    for (int fn = 0; fn < 4; ++fn) acc[fm][fn] = (f32x4){0.f, 0.f, 0.f, 0.f};

  const int n0 = split * (N_ / NSPLIT);
  const int lrow = l & 15;
  const int KS = (N_ / NSPLIT) / 64;  // 4

  float va[2][8];
  ushort ub[2][8];

#pragma unroll
  for (int q = 0; q < 2; ++q) {
    const float* g = Abase + (size_t)(n0 + (nb0 + q * 4) * 8) * C_ + cA;
#pragma unroll
    for (int kk = 0; kk < 8; ++kk) va[q][kk] = g[(size_t)kk * C_];
  }
#pragma unroll
  for (int q = 0; q < 2; ++q) {
    const ushort* g = Bbase + (size_t)(n0 + (nb0 + q * 4) * 8) * KV_ + jg;
#pragma unroll
    for (int kk = 0; kk < 8; ++kk) ub[q][kk] = g[(size_t)kk * KV_];
  }

  for (int ks = 0; ks < KS; ++ks) {
    bfpack pa[2], pb[2];
#pragma unroll
    for (int q = 0; q < 2; ++q)
#pragma unroll
      for (int p = 0; p < 4; ++p) pa[q].u[p] = cvtpk(va[q][2 * p], va[q][2 * p + 1]);
#pragma unroll
    for (int q = 0; q < 2; ++q)
#pragma unroll
      for (int kk = 0; kk < 8; ++kk) pb[q].s[kk] = ub[q][kk];

    __builtin_amdgcn_s_barrier();

#pragma unroll
    for (int q = 0; q < 2; ++q) {
      const int nb = nb0 + q * 4;
      *(bf16x8*)(As + cA * 64 + ((nb ^ (cA & 7)) << 3)) = pa[q].v;
      *(bf16x8*)(Bs + jB * 64 + ((nb ^ (jB & 7)) << 3)) = pb[q].v;
    }

    if (ks + 1 < KS) {
      const int nb1 = n0 + (ks + 1) * 64;
#pragma unroll
      for (int q = 0; q < 2; ++q) {
        const float* g = Abase + (size_t)(nb1 + (nb0 + q * 4) * 8) * C_ + cA;
#pragma unroll
        for (int kk = 0; kk < 8; ++kk) va[q][kk] = g[(size_t)kk * C_];
      }
#pragma unroll
      for (int q = 0; q < 2; ++q) {
        const ushort* g = Bbase + (size_t)(nb1 + (nb0 + q * 4) * 8) * KV_ + jg;
#pragma unroll
        for (int kk = 0; kk < 8; ++kk) ub[q][kk] = g[(size_t)kk * KV_];
      }
    }

    asm volatile("s_waitcnt lgkmcnt(0)" ::: "memory");
    __builtin_amdgcn_sched_barrier(0);
    __builtin_amdgcn_s_barrier();

#pragma unroll
    for (int half = 0; half < 2; ++half) {
      const int kb = half * 4 + (l >> 4);
      bf16x8 af[2], bv[4];
#pragma unroll
      for (int fm = 0; fm < 2; ++fm) {
        const int i = wm * 32 + fm * 16 + lrow;
        af[fm] = *(const bf16x8*)(As + i * 64 + ((kb ^ (i & 7)) << 3));
      }
#pragma unroll
      for (int fn = 0; fn < 4; ++fn) {
        const int j = wn * 64 + fn * 16 + lrow;
        bv[fn] = *(const bf16x8*)(Bs + j * 64 + ((kb ^ (j & 7)) << 3));
      }
#pragma unroll
      for (int fm = 0; fm < 2; ++fm)
#pragma unroll
        for (int fn = 0; fn < 4; ++fn)
          acc[fm][fn] = __builtin_amdgcn_mfma_f32_16x16x32_bf16(af[fm], bv[fn],
                                                                acc[fm][fn], 0, 0, 0);
    }
  }
  f32x4* Pv4 = (f32x4*)P + ((size_t)(split * 32 + bh) * 2 + jh) * 4096;
#pragma unroll
  for (int fm = 0; fm < 2; ++fm)
#pragma unroll
    for (int fn = 0; fn < 4; ++fn) Pv4[(fm * 4 + fn) * 512 + t] = acc[fm][fn];
}

// ---------------------------------------------------------------------------
// Reduce NSPLIT fragment-native partials and un-swizzle into S[bh][128][240].
// ---------------------------------------------------------------------------
__global__ __launch_bounds__(256) void k_reduce_frag(const f32x4* __restrict__ P,
                                                     float* __restrict__ S) {
  const int bh = blockIdx.x;
  const int g = blockIdx.y * 256 + threadIdx.x;
  const int jh = g >> 12;
  const int rest = g & 4095;
  f32x4 a = P[((size_t)bh * 2 + jh) * 4096 + rest];
#pragma unroll
  for (int s = 1; s < NSPLIT; ++s) {
    f32x4 v = P[((size_t)(s * 32 + bh) * 2 + jh) * 4096 + rest];
    a.x += v.x; a.y += v.y; a.z += v.z; a.w += v.w;
  }
  const int v = rest >> 9, tt = rest & 511;
  const int fm = v >> 2, fn = v & 3;
  const int wv = tt >> 6, l = tt & 63;
  const int wm = wv >> 1, wn = wv & 1;
  const int i0 = wm * 32 + fm * 16 + (l >> 4) * 4;
  const int j = jh * 128 + wn * 64 + fn * 16 + (l & 15);
  if (j < DK) {
    float* sp = S + (size_t)bh * (DQ * DK) + (size_t)i0 * DK + j;
    sp[0] = a.x; sp[DK] = a.y; sp[2 * DK] = a.z; sp[3 * DK] = a.w;
  }
}

// ---------------------------------------------------------------------------
// f32 -> bf16 (RNE), 4 elems/thread
// ---------------------------------------------------------------------------
__global__ __launch_bounds__(256) void k_cvt(const float4* __restrict__ in,
                                             ushort4* __restrict__ out, int n4) {
  int i = blockIdx.x * 256 + threadIdx.x;
  if (i >= n4) return;
  float4 v = in[i];
  ushort4 o;
  o.x = f2bf(v.x); o.y = f2bf(v.y); o.z = f2bf(v.z); o.w = f2bf(v.w);
  out[i] = o;
}

// ===========================================================================
// Flat-batched f32 chain GEMMs (unchanged from R6).
// ===========================================================================
__global__ __launch_bounds__(256) void k_g1(const float* __restrict__ Wq,
                                            const float* __restrict__ S,
                                            float* __restrict__ U) {
  const int h = blockIdx.x, c0 = blockIdx.y * 64;
  const int b = blockIdx.z / 5, n0 = (blockIdx.z % 5) * 48;
  const float* A = Wq + (size_t)h * 16384;
  const float* Bp = S + (size_t)(b * 4 + h) * 30720 + n0;
  float* Cp = U + (size_t)(b * 4 + h) * 30720 + n0;
  __shared__ float Ast[16][65];
  __shared__ float Bst[16][49];
  const int t = threadIdx.x;
  const int mi = (t >> 4) * 4, nj = (t & 15) * 3;
  float acc[4][3] = {};
  for (int k0 = 0; k0 < 128; k0 += 16) {
    __syncthreads();
#pragma unroll
    for (int q = 0; q < 4; ++q) {
      int idx = t + q * 256, m = idx >> 4, k = idx & 15;
      Ast[k][m] = A[(size_t)(c0 + m) * 128 + k0 + k];
    }
#pragma unroll
    for (int q = 0; q < 3; ++q) {
      int idx = t + q * 256, k = idx / 48, n = idx % 48;
      Bst[k][n] = Bp[(size_t)(k0 + k) * 240 + n];
    }
    __syncthreads();
#pragma unroll
    for (int kk = 0; kk < 16; ++kk) {
      float a4[4], b3[3];
#pragma unroll
      for (int x = 0; x < 4; ++x) a4[x] = Ast[kk][mi + x];
#pragma unroll
      for (int y = 0; y < 3; ++y) b3[y] = Bst[kk][nj + y];
#pragma unroll
      for (int x = 0; x < 4; ++x)
#pragma unroll
        for (int y = 0; y < 3; ++y) acc[x][y] = fmaf(a4[x], b3[y], acc[x][y]);
    }
  }
#pragma unroll
  for (int x = 0; x < 4; ++x)
#pragma unroll
    for (int y = 0; y < 3; ++y)
      Cp[(size_t)(c0 + mi + x) * 240 + nj + y] = acc[x][y];
}

__global__ __launch_bounds__(256) void k_g2(const float* __restrict__ U,
                                            const float* __restrict__ Wk,
                                            float* __restrict__ SC) {
  const int m0 = blockIdx.x * 64, n0 = blockIdx.y * 48;
  __shared__ float Ast[16][65];
  __shared__ float Bst2[48][17];
  const int t = threadIdx.x;
  const int mi = (t >> 4) * 4, nj = (t & 15) * 3;
  float acc[4][3] = {};
  for (int k0 = 0; k0 < 240; k0 += 16) {
    __syncthreads();
#pragma unroll
    for (int q = 0; q < 4; ++q) {
      int idx = t + q * 256, m = idx >> 4, k = idx & 15;
      Ast[k][m] = U[(size_t)(m0 + m) * 240 + k0 + k];
    }
#pragma unroll
    for (int q = 0; q < 3; ++q) {
      int idx = t + q * 256, n = idx >> 4, kd = idx & 15;
      Bst2[n][kd] = Wk[(size_t)(n0 + n) * 240 + k0 + kd];
    }
    __syncthreads();
#pragma unroll
    for (int kk = 0; kk < 16; ++kk) {
      float a4[4], b3[3];
#pragma unroll
      for (int x = 0; x < 4; ++x) a4[x] = Ast[kk][mi + x];
#pragma unroll
      for (int y = 0; y < 3; ++y) b3[y] = Bst2[nj + y][kk];
#pragma unroll
      for (int x = 0; x < 4; ++x)
#pragma unroll
        for (int y = 0; y < 3; ++y) acc[x][y] = fmaf(a4[x], b3[y], acc[x][y]);
    }
  }
  const float scale = 0.0322748612183951f;
#pragma unroll
  for (int x = 0; x < 4; ++x)
#pragma unroll
    for (int y = 0; y < 3; ++y)
      SC[(size_t)(m0 + mi + x) * 240 + n0 + nj + y] = acc[x][y] * scale;
}

__global__ __launch_bounds__(256) void k_g3(const float* __restrict__ PR,
                                            const float* __restrict__ Wv,
                                            float* __restrict__ T) {
  const int m0 = blockIdx.x * 64, n0 = blockIdx.y * 48;
  __shared__ float Ast[16][65];
  __shared__ float Bst[16][49];
  const int t = threadIdx.x;
  const int mi = (t >> 4) * 4, nj = (t & 15) * 3;
  float acc[4][3] = {};
  for (int k0 = 0; k0 < 240; k0 += 16) {
    __syncthreads();
#pragma unroll
    for (int q = 0; q < 4; ++q) {
      int idx = t + q * 256, m = idx >> 4, k = idx & 15;
      Ast[k][m] = PR[(size_t)(m0 + m) * 240 + k0 + k];
    }
#pragma unroll
    for (int q = 0; q < 3; ++q) {
      int idx = t + q * 256, k = idx / 48, n = idx % 48;
      Bst[k][n] = Wv[(size_t)(k0 + k) * 240 + n0 + n];
    }
    __syncthreads();
#pragma unroll
    for (int kk = 0; kk < 16; ++kk) {
      float a4[4], b3[3];
#pragma unroll
      for (int x = 0; x < 4; ++x) a4[x] = Ast[kk][mi + x];
#pragma unroll
      for (int y = 0; y < 3; ++y) b3[y] = Bst[kk][nj + y];
#pragma unroll
      for (int x = 0; x < 4; ++x)
#pragma unroll
        for (int y = 0; y < 3; ++y) acc[x][y] = fmaf(a4[x], b3[y], acc[x][y]);
    }
  }
#pragma unroll
  for (int x = 0; x < 4; ++x)
#pragma unroll
    for (int y = 0; y < 3; ++y)
      T[(size_t)(m0 + mi + x) * 240 + n0 + nj + y] = acc[x][y];
}

__global__ __launch_bounds__(256) void k_g4(const float* __restrict__ Wo,
                                            const float* __restrict__ T,
                                            ushort* __restrict__ W3bf) {
  const int h = blockIdx.x, e0 = blockIdx.y * 64;
  const int b = blockIdx.z / 5, n0 = (blockIdx.z % 5) * 48;
  const float* Bp = T + (size_t)(b * 4 + h) * 30720 + n0;
  ushort* Cp = W3bf + (size_t)b * 491520 + h * 240 + n0;
  __shared__ float Ast[16][65];
  __shared__ float Bst[16][49];
  const int t = threadIdx.x;
  const int mi = (t >> 4) * 4, nj = (t & 15) * 3;
  float acc[4][3] = {};
  for (int k0 = 0; k0 < 128; k0 += 16) {
    __syncthreads();
#pragma unroll
    for (int q = 0; q < 4; ++q) {
      int idx = t + q * 256, m = idx >> 4, k = idx & 15;
      Ast[k][m] = Wo[(size_t)(e0 + m) * 512 + 4 * (k0 + k) + h];
    }
#pragma unroll
    for (int q = 0; q < 3; ++q) {
      int idx = t + q * 256, k = idx / 48, n = idx % 48;
      Bst[k][n] = Bp[(size_t)(k0 + k) * 240 + n];
    }
    __syncthreads();
#pragma unroll
    for (int kk = 0; kk < 16; ++kk) {
      float a4[4], b3[3];
#pragma unroll
      for (int x = 0; x < 4; ++x) a4[x] = Ast[kk][mi + x];
#pragma unroll
      for (int y = 0; y < 3; ++y) b3[y] = Bst[kk][nj + y];
#pragma unroll
      for (int x = 0; x < 4; ++x)
#pragma unroll
        for (int y = 0; y < 3; ++y) acc[x][y] = fmaf(a4[x], b3[y], acc[x][y]);
    }
  }
#pragma unroll
  for (int x = 0; x < 4; ++x)
#pragma unroll
    for (int y = 0; y < 3; ++y)
      Cp[(size_t)(e0 + mi + x) * 960 + nj + y] = f2bf(acc[x][y]);
}

// ---------------------------------------------------------------------------
// Stats + softmax (unchanged from R6).
// ---------------------------------------------------------------------------
__global__ __launch_bounds__(1024) void k_stats(const float* __restrict__ SC,
                                                float* __restrict__ stats) {
  const int bh = blockIdx.x;
  const float* s = SC + (size_t)bh * 30720;
  const int t = threadIdx.x;
  float sum = 0.f, sq = 0.f;
  for (int i = t; i < 30720; i += 1024) {
    float v = s[i];
    sum += v;
    sq = fmaf(v, v, sq);
  }
#pragma unroll
  for (int o = 32; o > 0; o >>= 1) {
    sum += __shfl_down(sum, o);
    sq += __shfl_down(sq, o);
  }
  __shared__ float s1[16], s2[16];
  if ((t & 63) == 0) { s1[t >> 6] = sum; s2[t >> 6] = sq; }
  __syncthreads();
  if (t == 0) {
    float ts = 0.f, tq = 0.f;
#pragma unroll
    for (int i = 0; i < 16; ++i) { ts += s1[i]; tq += s2[i]; }
    const float mu = ts * (1.f / 30720.f);
    const float var = tq * (1.f / 30720.f) - mu * mu;
    stats[bh * 2] = mu;
    stats[bh * 2 + 1] = rsqrtf(var + 1e-5f);
  }
}

__global__ __launch_bounds__(512) void k_softmax(const float* __restrict__ SC,
                                                 const float* __restrict__ stats,
                                                 float* __restrict__ PR) {
  const int bh = blockIdx.x;
  const float mu = stats[bh * 2], rstd = stats[bh * 2 + 1];
  const int wv = threadIdx.x >> 6, l = threadIdx.x & 63;
  const int row0 = blockIdx.y * 32 + wv * 4;
  const float* s = SC + (size_t)bh * 30720;
  float* p = PR + (size_t)bh * 30720;
#pragma unroll
  for (int r = 0; r < 4; ++r) {
    const float* srow = s + (size_t)(row0 + r) * 240;
    float* prow = p + (size_t)(row0 + r) * 240;
    float x0 = (srow[l] - mu) * rstd;
    float x1 = (srow[64 + l] - mu) * rstd;
    float x2 = (srow[128 + l] - mu) * rstd;
    float x3 = (l < 48) ? (srow[192 + l] - mu) * rstd : -1e30f;
    float m = fmaxf(fmaxf(x0, x1), fmaxf(x2, x3));
#pragma unroll
    for (int o = 32; o > 0; o >>= 1) m = fmaxf(m, __shfl_xor(m, o));
    float e0 = __expf(x0 - m), e1 = __expf(x1 - m), e2 = __expf(x2 - m);
    float e3 = (l < 48) ? __expf(x3 - m) : 0.f;
    float ss = e0 + e1 + e2 + e3;
#pragma unroll
    for (int o = 32; o > 0; o >>= 1) ss += __shfl_xor(ss, o);
    const float inv = 1.f / ss;
    prow[l] = e0 * inv;
    prow[64 + l] = e1 * inv;
    prow[128 + l] = e2 * inv;
    if (l < 48) prow[192 + l] = e3 * inv;
  }
}

// ---------------------------------------------------------------------------
// K3 (MFMA, 256x256 tile, 3-buffer counted-vmcnt pipeline, conflict-free):
//   O1[b,n,e] = sum_g embaBF[b,n,g] * W3bf[b,e,g]
// grid 256 (= 1 block/CU), block 512 (8 waves 2x4; wave tile 128x64), BK=32.
// Staged bytes halve vs 128^2 (128 FLOP/B). Per iter:
//   vmcnt(4) | s_barrier | STAGE(ks+2 -> buf (ks+2)%3) | ds_read+32 MFMA(buf)
// One barrier/iter; vmcnt never 0 in steady state; 2-iter latency budget.
// LDS 3 x (16KB A + 16KB B) = 96KB. Lane-read-order groups: 0 conflicts.
// ---------------------------------------------------------------------------
__global__ __launch_bounds__(512) void k3_mfma(const ushort* __restrict__ A,
                                               const ushort* __restrict__ Bw,
                                               float* __restrict__ C) {
  __shared__ ushort LDSu[3][16384];  // [buf][A 8192 us | B 8192 us]
  const int bid = blockIdx.x;
  const int swz = (bid & 7) * 32 + (bid >> 3);  // 256 blocks: each XCD owns one b
  const int b = swz >> 5;
  const int rem = swz & 31;
  const int mt = rem >> 1, nt = rem & 1;
  const int t = threadIdx.x;
  const int w = t >> 6, l = t & 63;
  const int wr = w >> 2, wc = w & 3;  // wave tile: rows wr*128, cols wc*64

  const ushort* Ab = A + (size_t)b * N_ * KV_ + (size_t)mt * 256 * KV_;
  const ushort* Bb = Bw + (size_t)b * C_ * KV_ + (size_t)nt * 256 * KV_;

  const int r_l = l & 15;        // staging row within 16-row group
  const int c_l = (l >> 4) * 8;  // staging k-chunk (elems)

#define K3STAGE(k0, bf)                                                        \
  do {                                                                         \
    _Pragma("unroll") for (int inst = 0; inst < 2; ++inst) {                   \
      const int g = w * 2 + inst; /* group 0..15 */                            \
      const ushort* ga = Ab + (size_t)(g * 16 + r_l) * KV_ + (k0) + c_l;       \
      __builtin_amdgcn_global_load_lds(                                        \
          (AS1 const uint32_t*)(uintptr_t)ga,                                  \
          (AS3 uint32_t*)(uintptr_t)(&LDSu[bf][0] + g * 512), 16, 0, 0);       \
      const ushort* gb = Bb + (size_t)(g * 16 + r_l) * KV_ + (k0) + c_l;       \
      __builtin_amdgcn_global_load_lds(                                        \
          (AS1 const uint32_t*)(uintptr_t)gb,                                  \
          (AS3 uint32_t*)(uintptr_t)(&LDSu[bf][8192] + g * 512), 16, 0, 0);    \
    }                                                                          \
  } while (0)

  f32x4 acc[8][4];
#pragma unroll
  for (int fm = 0; fm < 8; ++fm)
#pragma unroll
    for (int fn = 0; fn < 4; ++fn) acc[fm][fn] = (f32x4){0.f, 0.f, 0.f, 0.f};

  // prologue: tiles 0,1 in flight (8 loads/wave)
  K3STAGE(0, 0);
  K3STAGE(32, 1);

  const int NK = KV_ / 32;  // 30
  int cbuf = 0, sbuf = 2;
  for (int ks = 0; ks < NK; ++ks) {
    if (ks < NK - 1) asm volatile("s_waitcnt vmcnt(4)" ::: "memory");
    else             asm volatile("s_waitcnt vmcnt(0)" ::: "memory");
    __builtin_amdgcn_sched_barrier(0);
    __builtin_amdgcn_s_barrier();
    if (ks + 2 < NK) K3STAGE((ks + 2) * 32, sbuf);  // into iter(ks-1)'s buffer
    const ushort* Abase = &LDSu[cbuf][0];
    const ushort* Bbase = &LDSu[cbuf][8192];
    bf16x8 af[8], bv[4];
#pragma unroll
    for (int f = 0; f < 8; ++f)
      af[f] = *(const bf16x8*)(Abase + (wr * 8 + f) * 512 + l * 8);
#pragma unroll
    for (int f = 0; f < 4; ++f)
      bv[f] = *(const bf16x8*)(Bbase + (wc * 4 + f) * 512 + l * 8);
#pragma unroll
    for (int fm = 0; fm < 8; ++fm)
#pragma unroll
      for (int fn = 0; fn < 4; ++fn)
        acc[fm][fn] = __builtin_amdgcn_mfma_f32_16x16x32_bf16(af[fm], bv[fn],
                                                              acc[fm][fn], 0, 0, 0);
    cbuf = (cbuf == 2) ? 0 : cbuf + 1;
    sbuf = (sbuf == 2) ? 0 : sbuf + 1;
  }
#undef K3STAGE

  float* Cb = C + (size_t)b * N_ * C_ + ((size_t)mt * 256) * C_ + nt * 256;
  const int col = wc * 64 + (l & 15);
  const int rbase = wr * 128 + (l >> 4) * 4;
#pragma unroll
  for (int fm = 0; fm < 8; ++fm)
#pragma unroll
    for (int fn = 0; fn < 4; ++fn)
#pragma unroll
      for (int r = 0; r < 4; ++r)
        Cb[(size_t)(rbase + fm * 16 + r) * C_ + col + fn * 16] = acc[fm][fn][r];
}

// ---------------------------------------------------------------------------
// Memory plan (ws 78,643,200 B + d_out as scratch):
//   d_out [0, 67108864)     P frag-partials (NSPLIT=16, exact fit) -- dead
//                           before k3 overwrites
//   ws [0, 62914560)        embaBF (bf16), written FIRST
//   ws [62914560, 66846720) S (f32) -> then T (f32, after g1)
//   ws [66846720, 70778880) U (f32); stats overlays after g2; W3bf later
//   ws [70778880, 74711040) SC (f32) } W3bf (bf16) overlays U+SC in g4
//   ws [74711040, 78643200) PR (f32)
// ---------------------------------------------------------------------------
extern "C" void kernel_launch(void* const* d_in, const int* in_sizes, int n_in,
                              void* d_out, int out_size, void* d_ws, size_t ws_size,
                              hipStream_t stream) {
  const float* emb1 = (const float*)d_in[0];
  const float* emba = (const float*)d_in[1];
  const float* Wq   = (const float*)d_in[2];
  const float* Wk   = (const float*)d_in[3];
  const float* Wv   = (const float*)d_in[4];
  const float* Wo   = (const float*)d_in[5];
  float* out = (float*)d_out;
  char* ws = (char*)d_ws;

  ushort* embaBF = (ushort*)(ws);
  float*  S      = (float*)(ws + 62914560);
  float*  T      = (float*)(ws + 62914560);
  float*  U      = (float*)(ws + 66846720);
  ushort* W3bf   = (ushort*)(ws + 66846720);
  float*  SCb    = (float*)(ws + 70778880);
  float*  PRb    = (float*)(ws + 74711040);
  float*  P      = out;
  float*  stats  = (float*)(ws + 66846720);  // U region, dead after g2

  // 1) emb_all -> bf16 (feeds k1's B-gather and k3's A)
  k_cvt<<<30720, 256, 0, stream>>>((const float4*)emba, (ushort4*)embaBF, 7864320);

  // 2) S partials (MFMA, 4 blocks/CU) + reduce/unswizzle
  k1_mfma<<<dim3(32, NSPLIT, 2), 512, 0, stream>>>(emb1, embaBF, P);
  k_reduce_frag<<<dim3(32, 32), 256, 0, stream>>>((const f32x4*)P, S);

  // 3) chain (flat-batched f32 GEMMs + stats + softmax)
  k_g1<<<dim3(4, 2, 40), 256, 0, stream>>>(Wq, S, U);
  k_g2<<<dim3(64, 5), 256, 0, stream>>>(U, Wk, SCb);
  k_stats<<<32, 1024, 0, stream>>>(SCb, stats);
  k_softmax<<<dim3(32, 4), 512, 0, stream>>>(SCb, stats, PRb);
  k_g3<<<dim3(64, 5), 256, 0, stream>>>(PRb, Wv, T);
  k_g4<<<dim3(4, 8, 40), 256, 0, stream>>>(Wo, T, W3bf);

  // 4) O1[b] = embaBF[b] @ W3bf[b]^T  (MFMA 256^2, pipelined, XCD-swizzled)
  k3_mfma<<<256, 512, 0, stream>>>(embaBF, W3bf, out);
}